// Round 11
// baseline (469.027 us; speedup 1.0000x reference)
//
#include <hip/hip_runtime.h>
#include <hip/hip_bf16.h>
#include <math.h>

#define NN 16000
#define NPAD 16128
#define NE 256000
#define H 192
#define RP 256           // padded row: 64 lanes * 4 (bytes for fp8 tables)
#define KVR 512          // fused K/V row: 64 lanes * 8 bytes (K dword + V dword)
#define NL 4
#define NBATCH 8
#define VEt 8
#define HH (H*H)
#define EML 16

typedef __hip_bfloat16 bf16;
typedef unsigned short u16;
typedef unsigned char u8;
typedef unsigned int u32;
typedef __attribute__((ext_vector_type(8))) short bfrag_t;
typedef __attribute__((ext_vector_type(4))) float facc_t;
typedef __attribute__((ext_vector_type(4))) float f4;
typedef __attribute__((ext_vector_type(2))) unsigned int u32x2;
typedef __attribute__((ext_vector_type(2))) float f2v;

__device__ __forceinline__ bf16 f2b(float v){ return __float2bfloat16(v); }
__device__ __forceinline__ int rfl(int v){ return __builtin_amdgcn_readfirstlane(v); }

// ---- fp8 e4m3fn software encode, RTNE (fallback) ----
__device__ __forceinline__ unsigned enc8sw(float x){
    unsigned u = __float_as_uint(x);
    unsigned s = (u >> 24) & 0x80u;
    float ax = fabsf(x);
    if(ax >= 448.f) return s | 0x7Eu;
    if(ax < 0.015625f){
        int q = (int)rintf(ax * 512.f);
        return s | (unsigned)q;
    }
    unsigned au = u & 0x7FFFFFFFu;
    unsigned lsb = (au >> 20) & 1u;
    au += 0x7FFFFu + lsb;
    unsigned E = (au >> 23) - 127u;
    unsigned M = (au >> 20) & 7u;
    if((int)E > 8) return s | 0x7Eu;
    return s | ((E + 7u) << 3) | M;
}
__device__ __forceinline__ unsigned enc8(float x){
#if __has_builtin(__builtin_amdgcn_cvt_pk_fp8_f32)
    return (u32)__builtin_amdgcn_cvt_pk_fp8_f32(x, x, 0, false) & 0xFFu;
#else
    return enc8sw(x);
#endif
}
// pack 3 floats as fp8 into bytes 0..2 of a dword (byte 3 = junk, never read)
__device__ __forceinline__ u32 enc3(float f0, float f1, float f2){
#if __has_builtin(__builtin_amdgcn_cvt_pk_fp8_f32)
    u32 w = (u32)__builtin_amdgcn_cvt_pk_fp8_f32(f0, f1, 0, false);
    w = (u32)__builtin_amdgcn_cvt_pk_fp8_f32(f2, f2, (int)w, true);
    return w;
#else
    return enc8sw(f0) | (enc8sw(f1) << 8) | (enc8sw(f2) << 16);
#endif
}
template<int SEL>
__device__ __forceinline__ float dec8s(u32 w){
#if __has_builtin(__builtin_amdgcn_cvt_f32_fp8)
    return __builtin_amdgcn_cvt_f32_fp8((int)w, SEL);
#else
    unsigned v = (w >> (SEL*8)) & 0xFFu;
    unsigned e = (v >> 3) & 15u, m = v & 7u;
    float mag = e ? __builtin_ldexpf((float)(8u + m), (int)e - 10)
                  : __builtin_ldexpf((float)m, -9);
    return (v & 0x80u) ? -mag : mag;
#endif
}
// packed decode of bytes 0,1
__device__ __forceinline__ f2v dec8pk01(u32 w){
#if __has_builtin(__builtin_amdgcn_cvt_pk_f32_fp8)
    return __builtin_amdgcn_cvt_pk_f32_fp8((int)w, false);
#else
    f2v r; r.x = dec8s<0>(w); r.y = dec8s<1>(w); return r;
#endif
}
__device__ __forceinline__ float frcp(float x){
#if __has_builtin(__builtin_amdgcn_rcpf)
    return __builtin_amdgcn_rcpf(x);
#else
    return 1.f/x;
#endif
}

__global__ void k_sentinel(float* __restrict__ out, float v){ out[0] = v; }

// ---------------- prep0: {weight transpose | tvec MLP | zero cnt} ----------------
// blocks [0,160): transpose (20 mats x 8 slices); [160,168): tvec; [168,231): zero
__global__ void k_prep0(const float* __restrict__ wq, const float* __restrict__ wk,
                        const float* __restrict__ wv, const float* __restrict__ wsk,
                        const float* __restrict__ w1, const float* __restrict__ now,
                        const float* __restrict__ ew2, u16* __restrict__ wt,
                        const int* __restrict__ tg, const float* __restrict__ tw1,
                        const float* __restrict__ tb1, const float* __restrict__ tw2,
                        const float* __restrict__ tb2, float* __restrict__ tvec,
                        int* __restrict__ cnt){
    int blk = blockIdx.x;
    if(blk < 160){
        int mat = blk >> 3, ys = blk & 7;
        if(mat < 18){
            const float* src;
            if(mat < 4)       src = wq  + (size_t)mat*HH;
            else if(mat < 8)  src = wk  + (size_t)(mat-4)*HH;
            else if(mat < 12) src = wv  + (size_t)(mat-8)*HH;
            else if(mat < 16) src = wsk + (size_t)(mat-12)*HH;
            else              src = w1  + (size_t)(mat-16)*HH;
            u16* dst = wt + (size_t)mat*HH;
            const int slice = HH/8;
            int base = ys*slice;
            for(int i = base + threadIdx.x; i < base + slice; i += blockDim.x){
                int k = i / H, n = i % H;
                bf16 b = f2b(src[i]);
                dst[n*H + k] = *(u16*)&b;
            }
        } else if(mat == 18){
            u16* dst = wt + (size_t)18*HH;
            const int slice = (32*192)/8;
            int base = ys*slice;
            for(int i = base + threadIdx.x; i < base + slice; i += blockDim.x){
                int k = i >> 5, n = i & 31;
                bf16 b = f2b(now[i]);
                dst[n*192 + k] = *(u16*)&b;
            }
        } else {
            u16* dst = wt + (size_t)18*HH + 32*192;
            const int slice = (16*192)/8;
            int base = ys*slice;
            for(int i = base + threadIdx.x; i < base + slice; i += blockDim.x){
                int k = i >> 4, n = i & 15;
                float v = (n < 8) ? ew2[k*8 + n] : 0.f;
                bf16 b = f2b(v);
                dst[n*192 + k] = *(u16*)&b;
            }
        }
    } else if(blk < 168){
        int b = blk - 160, j = threadIdx.x;
        __shared__ float emb[H], h1[H];
        float t = (float)tg[b];
        if(j < 96){
            float fr = __expf(-logf(10000.0f) * (float)j / 96.0f);
            float ang = t * fr;
            emb[j]      = sinf(ang);
            emb[j + 96] = cosf(ang);
        }
        __syncthreads();
        if(j < H){
            float acc = tb1[j];
            for(int k = 0; k < H; k++) acc += emb[k] * tw1[k*H + j];
            h1[j] = acc / (1.f + __expf(-acc));
        }
        __syncthreads();
        if(j < H){
            float acc2 = tb2[j];
            for(int k = 0; k < H; k++) acc2 += h1[k] * tw2[k*H + j];
            tvec[b*H + j] = acc2;
        }
    } else {
        int i = (blk - 168)*256 + threadIdx.x;
        if(i < NN+1) cnt[i] = 0;
    }
}

// ---------------- prep1: {init_x (float4) | count | e/c-tables} ----------------
// blocks [0,3000): init_x; [3000,4000): count; [4000,4320): tabs
__global__ void k_prep1(const float* __restrict__ nemb, const float* __restrict__ memb,
                        const float* __restrict__ tvec, const int* __restrict__ ntype,
                        const int* __restrict__ emask, const int* __restrict__ nbatch,
                        float* __restrict__ x, u16* __restrict__ xb,
                        const int* __restrict__ edst, int* __restrict__ cnt,
                        const float* __restrict__ eemb, const float* __restrict__ we,
                        const float* __restrict__ w1, const float* __restrict__ b1,
                        u16* __restrict__ etab, u16* __restrict__ ctab){
    int blk = blockIdx.x;
    if(blk < 3000){
        int idx4 = (blk*256 + threadIdx.x)*4;
        int n = idx4 / H, c = idx4 % H;
        f4 nv = *(const f4*)(nemb + (size_t)ntype[n]*H + c);
        f4 tv = *(const f4*)(tvec + (size_t)nbatch[n]*H + c);
        f4 mv = *(const f4*)(memb + (size_t)emask[n]*H + c);
        f4 v; v.x = nv.x+tv.x+mv.x; v.y = nv.y+tv.y+mv.y;
              v.z = nv.z+tv.z+mv.z; v.w = nv.w+tv.w+mv.w;
        *(f4*)(x + idx4) = v;
        bf16 b0 = f2b(v.x), b1v = f2b(v.y), b2 = f2b(v.z), b3 = f2b(v.w);
        u16* xbp = xb + idx4;
        xbp[0] = *(u16*)&b0; xbp[1] = *(u16*)&b1v; xbp[2] = *(u16*)&b2; xbp[3] = *(u16*)&b3;
    } else if(blk < 4000){
        int e = (blk - 3000)*256 + threadIdx.x;
        atomicAdd(&cnt[edst[e]], 1);
    } else {
        int blk2 = blk - 4000;
        int c = threadIdx.x;
        __shared__ float a[H];
        if(blk2 < NL*64){
            int l = blk2 >> 6, idx = blk2 & 63, b = idx >> 3, et = idx & 7;
            if(c < H) a[c] = eemb[et*H + c] + tvec[b*H + c];
            __syncthreads();
            if(c < H){
                float acc = 0.f;
                const float* w = we + (size_t)l*HH;
                for(int k = 0; k < H; k++) acc += a[k] * w[k*H + c];
                bf16 bv = f2b(acc);
                etab[(size_t)blk2*256 + (c/3)*4 + (c%3)] = *(u16*)&bv;
            }
        } else {
            int idx = blk2 - NL*64, b = idx >> 3, et = idx & 7;
            if(c < H) a[c] = eemb[et*H + c] + tvec[b*H + c];
            __syncthreads();
            if(c < H){
                float acc = b1[c];
                for(int k = 0; k < H; k++){
                    acc += a[k]          * w1[(size_t)(2*H + k)*H + c];
                    acc += tvec[b*H + k] * w1[(size_t)(3*H + k)*H + c];
                }
                bf16 bv = f2b(acc);
                ctab[(size_t)idx*256 + (c/3)*4 + (c%3)] = *(u16*)&bv;
            }
        }
    }
}

__global__ __launch_bounds__(1024) void k_scan(const int* __restrict__ cnt,
                                               int* __restrict__ ofs, int* __restrict__ cur){
    __shared__ int wsum[16];
    __shared__ int carry_s;
    int tid = threadIdx.x, lane = tid & 63, w = tid >> 6;
    if(tid == 0) carry_s = 0;
    __syncthreads();
    for(int base = 0; base < NN; base += 1024){
        int idx = base + tid;
        int v = (idx < NN) ? cnt[idx] : 0;
        int sc = v;
        #pragma unroll
        for(int o = 1; o < 64; o <<= 1){
            int t = __shfl_up(sc, o);
            if(lane >= o) sc += t;
        }
        if(lane == 63) wsum[w] = sc;
        __syncthreads();
        if(w == 0){
            int ws = (lane < 16) ? wsum[lane] : 0;
            #pragma unroll
            for(int o = 1; o < 16; o <<= 1){
                int t = __shfl_up(ws, o);
                if(lane >= o) ws += t;
            }
            if(lane < 16) wsum[lane] = ws;
        }
        __syncthreads();
        int wbase = (w > 0) ? wsum[w-1] : 0;
        int c = carry_s;
        int excl = c + wbase + sc - v;
        if(idx < NN){ ofs[idx] = excl; cur[idx] = excl; }
        __syncthreads();
        if(tid == 0) carry_s = c + wsum[15];
        __syncthreads();
    }
    if(threadIdx.x == 0) ofs[NN] = carry_s;
}
// spair: sorted-by-dst {s*KVR, ct*KVR}; eprep: per-original-edge {s*RP, d*RP, ct*KVR, 0}
__global__ void k_scatter(const int* __restrict__ esrc, const int* __restrict__ edst,
                          const int* __restrict__ etype, const int* __restrict__ nbatch,
                          int* __restrict__ cur, int2* __restrict__ spair, int4* __restrict__ eprep){
    int e = blockIdx.x*blockDim.x + threadIdx.x;
    if(e >= NE) return;
    int s = esrc[e], d = edst[e];
    int ct = (nbatch[s]*VEt + etype[e])*KVR;
    int pos = atomicAdd(&cur[d], 1);
    int2 se; se.x = s*KVR; se.y = ct;
    spair[pos] = se;
    eprep[e] = make_int4(s*RP, d*RP, ct, 0);
}

// ---------------- MFMA GEMM, group-owning B permutation ----------------
// Each thread's 3 j-accumulators hold 3 CONSECUTIVE output cols (one packed group):
// bg[j] = Wt row (nt*48 + l16*3 + j). N-tiles are 48 cols (4 tiles). One dword store
// per (i,r) instead of 12 scattered byte/u16 stores.
// obf: 2 = fp8 RP-row; 3 = fp8 KV-row K-half; 4 = fp8 KV-row V-half; 5 = bf16 packed 512B
struct GemmP {
    const u16* wt[4];
    const float* bias[4];
    void* out[4];
    int obf[4];
};
__global__ __launch_bounds__(256) void k_gemm(const u16* __restrict__ A, GemmP P){
    int oi = blockIdx.y >> 2, nt = blockIdx.y & 3;
    const u16* Wt = P.wt[oi];
    const float* bias = P.bias[oi];
    int wave = rfl(threadIdx.x >> 6), lane = threadIdx.x & 63;
    int quad = lane >> 4, l16 = lane & 15;
    int m0 = blockIdx.x*256 + wave*64;
    int nrow = nt*48 + l16*3;      // first of this thread's 3 output cols
    int g = nt*16 + l16;           // packed group index
    facc_t acc[4][3];
    #pragma unroll
    for(int i = 0; i < 4; i++)
        #pragma unroll
        for(int j = 0; j < 3; j++){ acc[i][j][0]=0.f; acc[i][j][1]=0.f; acc[i][j][2]=0.f; acc[i][j][3]=0.f; }
    #pragma unroll
    for(int kc = 0; kc < 6; kc++){
        int kb = kc*32 + quad*8;
        bfrag_t af[4], bg[3];
        #pragma unroll
        for(int i = 0; i < 4; i++) af[i] = *(const bfrag_t*)(A  + (size_t)(m0 + i*16 + l16)*H + kb);
        #pragma unroll
        for(int j = 0; j < 3; j++) bg[j] = *(const bfrag_t*)(Wt + (size_t)(nrow + j)*H + kb);
        #pragma unroll
        for(int i = 0; i < 4; i++)
            #pragma unroll
            for(int j = 0; j < 3; j++)
                acc[i][j] = __builtin_amdgcn_mfma_f32_16x16x32_bf16(af[i], bg[j], acc[i][j], 0, 0, 0);
    }
    float bv0 = bias ? bias[nrow]     : 0.f;
    float bv1 = bias ? bias[nrow + 1] : 0.f;
    float bv2 = bias ? bias[nrow + 2] : 0.f;
    int mode = P.obf[oi];
    #pragma unroll
    for(int i = 0; i < 4; i++){
        int rb = m0 + i*16 + quad*4;
        #pragma unroll
        for(int r = 0; r < 4; r++){
            int row = rb + r;
            if(row >= NN) continue;
            float f0 = acc[i][0][r] + bv0;
            float f1 = acc[i][1][r] + bv1;
            float f2 = acc[i][2][r] + bv2;
            if(mode == 5){
                bf16 h0 = f2b(f0), h1 = f2b(f1), h2 = f2b(f2);
                u32x2 d;
                d.x = (u32)*(u16*)&h0 | ((u32)*(u16*)&h1 << 16);
                d.y = (u32)*(u16*)&h2;
                *(u32x2*)((u8*)P.out[oi] + (size_t)row*512 + g*8) = d;
            } else if(mode == 2){
                *(u32*)((u8*)P.out[oi] + (size_t)row*256 + g*4) = enc3(f0, f1, f2);
            } else {
                int koff = (mode == 4) ? 4 : 0;
                *(u32*)((u8*)P.out[oi] + (size_t)row*512 + g*8 + koff) = enc3(f0, f1, f2);
            }
        }
    }
}

// ---------------- fused attention + gate + LN; pipelined, cached gathers ----------------
// Qb/XRp: bf16 packed 512B rows; KVb: 512B fp8 rows; etab: bf16 512B rows (L1)
__global__ __launch_bounds__(256) void k_attn(
    const u8* __restrict__ Qb, const u8* __restrict__ KVb,
    const u8* __restrict__ XRp,
    const u16* __restrict__ etab, const int* __restrict__ ofs,
    const int2* __restrict__ spair,
    const float* __restrict__ wb, const float* __restrict__ lng, const float* __restrict__ lnb,
    float* __restrict__ x, u16* __restrict__ xb)
{
    int wv = rfl(threadIdx.x >> 6);
    int n = blockIdx.x*4 + wv;
    int lane = threadIdx.x & 63;
    int lane8 = lane*8;
    int ch = lane*3;
    size_t base = (size_t)n*H + ch;
    const float scale = 0.14433756729740646f;   // 1/sqrt(48)
    u32x2 qw = *(const u32x2*)(Qb + (size_t)n*512 + lane8);
    float q0 = __uint_as_float(qw.x << 16);
    float q1 = __uint_as_float(qw.x & 0xffff0000u);
    float q2 = __uint_as_float(qw.y << 16);
    int p0 = ofs[n], p1 = ofs[n+1];
    float lac[4]  = {0.f,0.f,0.f,0.f};
    float ac0[4]  = {0.f,0.f,0.f,0.f};
    float ac1[4]  = {0.f,0.f,0.f,0.f};
    float ac2[4]  = {0.f,0.f,0.f,0.f};
    const u8* etb = (const u8*)etab;
    int p = p0;
    u32x2 kvc[4], ewc[4];
    bool have = (p + 3 < p1);
    if(have){
        #pragma unroll
        for(int t = 0; t < 4; t++){
            int2 se = spair[p+t];
            kvc[t] = *(const u32x2*)(KVb + se.x + lane8);
            ewc[t] = *(const u32x2*)(etb + se.y + lane8);
        }
    }
    while(have){
        int pn = p + 4;
        bool more = (pn + 3 < p1);
        u32x2 kvn[4], ewn[4];
        if(more){
            #pragma unroll
            for(int t = 0; t < 4; t++){
                int2 se = spair[pn+t];
                kvn[t] = *(const u32x2*)(KVb + se.x + lane8);
                ewn[t] = *(const u32x2*)(etb + se.y + lane8);
            }
        }
        float e0[4], e1[4], e2[4], tt[4];
        #pragma unroll
        for(int t = 0; t < 4; t++){
            e0[t] = __uint_as_float(ewc[t].x << 16);
            e1[t] = __uint_as_float(ewc[t].x & 0xffff0000u);
            e2[t] = __uint_as_float(ewc[t].y << 16);
            f2v k01 = dec8pk01(kvc[t].x);
            float k2 = dec8s<2>(kvc[t].x);
            tt[t] = q0*(k01.x+e0[t]) + q1*(k01.y+e1[t]) + q2*(k2+e2[t]);
        }
        #pragma unroll
        for(int o = 1; o <= 8; o <<= 1){
            #pragma unroll
            for(int t = 0; t < 4; t++) tt[t] += __shfl_xor(tt[t], o);
        }
        #pragma unroll
        for(int t = 0; t < 4; t++){
            float sc = fminf(fmaxf(tt[t]*scale, -60.f), 60.f);
            float pw = __expf(sc);
            f2v v01 = dec8pk01(kvc[t].y);
            float v2 = dec8s<2>(kvc[t].y);
            lac[t] += pw;
            ac0[t] += pw*(v01.x+e0[t]);
            ac1[t] += pw*(v01.y+e1[t]);
            ac2[t] += pw*(v2+e2[t]);
        }
        if(more){
            #pragma unroll
            for(int t = 0; t < 4; t++){ kvc[t] = kvn[t]; ewc[t] = ewn[t]; }
        }
        p = pn;
        have = more;
    }
    for(; p < p1; p++){
        int soA = spair[p].x, eoA = spair[p].y;
        u32x2 kvA = *(const u32x2*)(KVb + soA + lane8);
        u32x2 ewA = *(const u32x2*)(etb + eoA + lane8);
        float e0A = __uint_as_float(ewA.x << 16);
        float e1A = __uint_as_float(ewA.x & 0xffff0000u);
        float e2A = __uint_as_float(ewA.y << 16);
        f2v k01 = dec8pk01(kvA.x);
        float k2 = dec8s<2>(kvA.x);
        float tA = q0*(k01.x+e0A) + q1*(k01.y+e1A) + q2*(k2+e2A);
        tA += __shfl_xor(tA,1); tA += __shfl_xor(tA,2); tA += __shfl_xor(tA,4); tA += __shfl_xor(tA,8);
        float sc = fminf(fmaxf(tA*scale, -60.f), 60.f);
        float pw = __expf(sc);
        f2v v01 = dec8pk01(kvA.y);
        float v2 = dec8s<2>(kvA.y);
        lac[0] += pw;
        ac0[0] += pw*(v01.x+e0A);
        ac1[0] += pw*(v01.y+e1A);
        ac2[0] += pw*(v2+e2A);
    }
    float l  = (lac[0]+lac[1]) + (lac[2]+lac[3]);
    float a0 = (ac0[0]+ac0[1]) + (ac0[2]+ac0[3]);
    float a1 = (ac1[0]+ac1[1]) + (ac1[2]+ac1[3]);
    float a2 = (ac2[0]+ac2[1]) + (ac2[2]+ac2[3]);
    float inv = (p1 > p0) ? 1.f/l : 0.f;
    float o0 = a0*inv, o1 = a1*inv, o2 = a2*inv;
    u32x2 xrw = *(const u32x2*)(XRp + (size_t)n*512 + lane8);
    float xr0 = __uint_as_float(xrw.x << 16);
    float xr1 = __uint_as_float(xrw.x & 0xffff0000u);
    float xr2 = __uint_as_float(xrw.y << 16);
    float sd = o0*wb[ch]  + o1*wb[ch+1]  + o2*wb[ch+2]
             + xr0*wb[H+ch] + xr1*wb[H+ch+1] + xr2*wb[H+ch+2]
             + (o0-xr0)*wb[2*H+ch] + (o1-xr1)*wb[2*H+ch+1] + (o2-xr2)*wb[2*H+ch+2];
    sd += __shfl_xor(sd,1); sd += __shfl_xor(sd,2); sd += __shfl_xor(sd,4);
    sd += __shfl_xor(sd,8); sd += __shfl_xor(sd,16); sd += __shfl_xor(sd,32);
    float beta = 1.f/(1.f + __expf(-sd));
    float h0 = beta*xr0 + (1.f-beta)*o0;
    float h1 = beta*xr1 + (1.f-beta)*o1;
    float h2 = beta*xr2 + (1.f-beta)*o2;
    float y0 = x[base] + h0, y1 = x[base+1] + h1, y2 = x[base+2] + h2;
    float s3 = y0 + y1 + y2;
    float q3 = y0*y0 + y1*y1 + y2*y2;
    #pragma unroll
    for(int o = 1; o <= 32; o <<= 1){
        s3 += __shfl_xor(s3, o);
        q3 += __shfl_xor(q3, o);
    }
    float mean = s3 * (1.f/H);
    float var = fmaxf(q3*(1.f/H) - mean*mean, 0.f);
    float rs = rsqrtf(var + 1e-5f);
    float d0 = y0-mean, d1 = y1-mean, d2 = y2-mean;
    float z0 = d0*rs*lng[ch]   + lnb[ch];
    float z1 = d1*rs*lng[ch+1] + lnb[ch+1];
    float z2 = d2*rs*lng[ch+2] + lnb[ch+2];
    x[base] = z0; x[base+1] = z1; x[base+2] = z2;
    bf16 t0 = f2b(z0), t1 = f2b(z1), t2 = f2b(z2);
    xb[base] = *(u16*)&t0; xb[base+1] = *(u16*)&t1; xb[base+2] = *(u16*)&t2;
}

// ---------------- node logits: MFMA (M=16128, N=32, K=192), A = xb bf16 ----------------
__global__ __launch_bounds__(256) void k_nodeout(const u16* __restrict__ A, const u16* __restrict__ Wt,
                                                 const float* __restrict__ b, float* __restrict__ out){
    int wave = rfl(threadIdx.x >> 6), lane = threadIdx.x & 63;
    int quad = lane >> 4, l16 = lane & 15;
    int m0 = blockIdx.x*256 + wave*64;
    facc_t acc[4][2];
    #pragma unroll
    for(int i = 0; i < 4; i++)
        #pragma unroll
        for(int j = 0; j < 2; j++){ acc[i][j][0]=0.f; acc[i][j][1]=0.f; acc[i][j][2]=0.f; acc[i][j][3]=0.f; }
    #pragma unroll
    for(int kc = 0; kc < 6; kc++){
        int kb = kc*32 + quad*8;
        bfrag_t af[4], bg[2];
        #pragma unroll
        for(int i = 0; i < 4; i++) af[i] = *(const bfrag_t*)(A  + (size_t)(m0 + i*16 + l16)*H + kb);
        #pragma unroll
        for(int j = 0; j < 2; j++) bg[j] = *(const bfrag_t*)(Wt + (size_t)(j*16 + l16)*H + kb);
        #pragma unroll
        for(int i = 0; i < 4; i++)
            #pragma unroll
            for(int j = 0; j < 2; j++)
                acc[i][j] = __builtin_amdgcn_mfma_f32_16x16x32_bf16(af[i], bg[j], acc[i][j], 0, 0, 0);
    }
    float bv[2];
    #pragma unroll
    for(int j = 0; j < 2; j++) bv[j] = b[j*16 + l16];
    #pragma unroll
    for(int i = 0; i < 4; i++){
        int rb = m0 + i*16 + quad*4;
        #pragma unroll
        for(int r = 0; r < 4; r++){
            int row = rb + r;
            if(row < NN){
                #pragma unroll
                for(int j = 0; j < 2; j++)
                    out[(size_t)row*32 + j*16 + l16] = acc[i][j][r] + bv[j];
            }
        }
    }
}

// ---------------- edge logits: eprep-driven gather+silu -> LDS bf16 -> MFMA ----------------
__global__ __launch_bounds__(256) void k_edgemlp(
    const int4* __restrict__ eprep,
    const u8* __restrict__ xs1, const u8* __restrict__ xd1, const u16* __restrict__ ctab,
    const u16* __restrict__ w2t, const float* __restrict__ b2p, float* __restrict__ out)
{
    __shared__ u16 hbuf[4][16][200];    // [wave][edge][192 bf16 + 8 pad]
    int wave = rfl(threadIdx.x >> 6);
    int lane = threadIdx.x & 63;
    int lane8 = lane*8;
    int l16 = lane & 15, quad = lane >> 4;
    int wid = blockIdx.x*4 + wave;
    int e0 = wid*EML;
    const u8* ctb = (const u8*)ctab;
    bfrag_t bg[6];
    #pragma unroll
    for(int kc = 0; kc < 6; kc++)
        bg[kc] = *(const bfrag_t*)(w2t + (size_t)l16*192 + kc*32 + quad*8);
    for(int eb = 0; eb < EML; eb += 2){
        int4 epX = eprep[e0 + eb];
        int4 epY = eprep[e0 + eb + 1];
        u32 awX = *(const u32*)(xs1 + epX.x + lane*4);
        u32 awY = *(const u32*)(xs1 + epY.x + lane*4);
        u32 bwX = *(const u32*)(xd1 + epX.y + lane*4);
        u32 bwY = *(const u32*)(xd1 + epY.y + lane*4);
        u32x2 cwX = *(const u32x2*)(ctb + epX.z + lane8);
        u32x2 cwY = *(const u32x2*)(ctb + epY.z + lane8);
        float cfX0 = __uint_as_float(cwX.x << 16);
        float cfX1 = __uint_as_float(cwX.x & 0xffff0000u);
        float cfX2 = __uint_as_float(cwX.y << 16);
        float cfY0 = __uint_as_float(cwY.x << 16);
        float cfY1 = __uint_as_float(cwY.x & 0xffff0000u);
        float cfY2 = __uint_as_float(cwY.y << 16);
        f2v aX = dec8pk01(awX), bX = dec8pk01(bwX);
        f2v aY = dec8pk01(awY), bY = dec8pk01(bwY);
        float aX2 = dec8s<2>(awX), bX2 = dec8s<2>(bwX);
        float aY2 = dec8s<2>(awY), bY2 = dec8s<2>(bwY);
        float hX0, hX1, hX2, hY0, hY1, hY2;
        { float v = aX.x+bX.x+cfX0; hX0 = v*frcp(1.f+__expf(-v)); }
        { float v = aX.y+bX.y+cfX1; hX1 = v*frcp(1.f+__expf(-v)); }
        { float v = aX2 +bX2 +cfX2; hX2 = v*frcp(1.f+__expf(-v)); }
        { float v = aY.x+bY.x+cfY0; hY0 = v*frcp(1.f+__expf(-v)); }
        { float v = aY.y+bY.y+cfY1; hY1 = v*frcp(1.f+__expf(-v)); }
        { float v = aY2 +bY2 +cfY2; hY2 = v*frcp(1.f+__expf(-v)); }
        u16* rowX = &hbuf[wave][eb][0];
        u16* rowY = &hbuf[wave][eb+1][0];
        bf16 x0 = f2b(hX0), x1 = f2b(hX1), x2 = f2b(hX2);
        bf16 y0 = f2b(hY0), y1 = f2b(hY1), y2 = f2b(hY2);
        rowX[lane*3+0] = *(u16*)&x0; rowX[lane*3+1] = *(u16*)&x1; rowX[lane*3+2] = *(u16*)&x2;
        rowY[lane*3+0] = *(u16*)&y0; rowY[lane*3+1] = *(u16*)&y1; rowY[lane*3+2] = *(u16*)&y2;
    }
    __syncthreads();
    facc_t acc;
    acc[0]=0.f; acc[1]=0.f; acc[2]=0.f; acc[3]=0.f;
    #pragma unroll
    for(int kc = 0; kc < 6; kc++){
        bfrag_t af = *(const bfrag_t*)&hbuf[wave][l16][kc*32 + quad*8];
        acc = __builtin_amdgcn_mfma_f32_16x16x32_bf16(af, bg[kc], acc, 0, 0, 0);
    }
    if(l16 < 8){
        float bo = b2p[l16];
        #pragma unroll
        for(int r = 0; r < 4; r++){
            int e = e0 + quad*4 + r;
            out[(size_t)e*8 + l16] = acc[r] + bo;
        }
    }
}

extern "C" void kernel_launch(void* const* d_in, const int* in_sizes, int n_in,
                              void* d_out, int out_size, void* d_ws, size_t ws_size,
                              hipStream_t stream)
{
    {
        int bad = -1;
        if(n_in != 31) bad = 100;
        else {
            const int chk_idx[9] = {0, 7, 16, 21, 23, 26, 27, 29, 30};
            const int chk_sz [9] = {32*H, NL*HH, NL*3*H, 4*HH, H*8, NE, 2*NE, NN, NBATCH};
            for(int i = 0; i < 9; i++) if(in_sizes[chk_idx[i]] != chk_sz[i]){ bad = chk_idx[i]; break; }
        }
        if(bad >= 0){ k_sentinel<<<1,1,0,stream>>>((float*)d_out, 20000.f + 256.f*bad); return; }
        if(out_size != NN*32 + NE*8){ k_sentinel<<<1,1,0,stream>>>((float*)d_out, 30000.f); return; }
    }

    const float* node_emb = (const float*)d_in[0];
    const float* edge_emb = (const float*)d_in[1];
    const float* time_w1  = (const float*)d_in[2];
    const float* time_b1  = (const float*)d_in[3];
    const float* time_w2  = (const float*)d_in[4];
    const float* time_b2  = (const float*)d_in[5];
    const float* mask_emb = (const float*)d_in[6];
    const float* wq       = (const float*)d_in[7];
    const float* bq       = (const float*)d_in[8];
    const float* wk       = (const float*)d_in[9];
    const float* bk       = (const float*)d_in[10];
    const float* wv       = (const float*)d_in[11];
    const float* bv       = (const float*)d_in[12];
    const float* we       = (const float*)d_in[13];
    const float* wskip    = (const float*)d_in[14];
    const float* bskip    = (const float*)d_in[15];
    const float* wbeta    = (const float*)d_in[16];
    const float* ln_g     = (const float*)d_in[17];
    const float* ln_b     = (const float*)d_in[18];
    const float* now      = (const float*)d_in[19];
    const float* nob      = (const float*)d_in[20];
    const float* ew1      = (const float*)d_in[21];
    const float* eb1      = (const float*)d_in[22];
    const float* ew2      = (const float*)d_in[23];
    const float* eb2      = (const float*)d_in[24];
    const int* node_type  = (const int*)d_in[25];
    const int* edge_type  = (const int*)d_in[26];
    const int* edge_index = (const int*)d_in[27];
    const int* edit_mask  = (const int*)d_in[28];
    const int* node_batch = (const int*)d_in[29];
    const int* t_graph    = (const int*)d_in[30];
    const int* esrc = edge_index;
    const int* edst = edge_index + NE;

    char* wsb = (char*)d_ws;
    size_t off = 0;
    auto take = [&](size_t bytes) -> char* {
        char* r = wsb + off;
        off += (bytes + 255) & ~(size_t)255;
        return r;
    };
    float* tvec = (float*)take((size_t)NBATCH*H*4);
    float* x    = (float*)take((size_t)NN*H*4);
    u16*   xb   = (u16*)  take((size_t)NPAD*H*2);
    u8*    Qb   = (u8*)   take((size_t)NN*512);
    u8*    KVb  = (u8*)   take((size_t)NN*KVR);
    u8*    XRp  = (u8*)   take((size_t)NN*512);
    u8*    xs1  = (u8*)   take((size_t)NN*RP);
    u8*    xd1  = (u8*)   take((size_t)NN*RP);
    u16*   etab = (u16*)  take((size_t)NL*64*KVR);
    u16*   ctab = (u16*)  take((size_t)64*KVR);
    u16*   wt   = (u16*)  take((size_t)(18*HH + 32*192 + 16*192)*2);
    int* cnt    = (int*)  take((size_t)(NN+1)*4);
    int* offa   = (int*)  take((size_t)(NN+1)*4);
    int* cur    = (int*)  take((size_t)(NN+1)*4);
    int2* spair = (int2*) take((size_t)NE*8);
    int4* eprep = (int4*) take((size_t)NE*16);

    if(ws_size < off){
        k_sentinel<<<1,1,0,stream>>>((float*)d_out, 10000.f + (float)(ws_size >> 20));
        return;
    }

    u16* w32t = wt + (size_t)18*HH;          // [32][192] bf16 (node_out_w^T)
    u16* w2t  = w32t + 32*192;               // [16][192] bf16 (edge_w2^T, zero-padded)

    k_prep0<<<231, 256, 0, stream>>>(wq, wk, wv, wskip, ew1, now, ew2, wt,
                                     t_graph, time_w1, time_b1, time_w2, time_b2, tvec, cnt);
    k_prep1<<<4320, 256, 0, stream>>>(node_emb, mask_emb, tvec, node_type, edit_mask, node_batch,
                                      x, xb, edst, cnt, edge_emb, we, ew1, eb1, etab, ctab);
    k_scan<<<1, 1024, 0, stream>>>(cnt, offa, cur);
    k_scatter<<<NE/256, 256, 0, stream>>>(esrc, edst, edge_type, node_batch, cur, spair, eprep);

    for(int l = 0; l < NL; l++){
        GemmP P;
        P.wt[0] = wt + (size_t)(0  + l)*HH;  P.bias[0] = bq   + (size_t)l*H;  P.out[0] = Qb;  P.obf[0] = 5;
        P.wt[1] = wt + (size_t)(4  + l)*HH;  P.bias[1] = bk   + (size_t)l*H;  P.out[1] = KVb; P.obf[1] = 3;
        P.wt[2] = wt + (size_t)(8  + l)*HH;  P.bias[2] = bv   + (size_t)l*H;  P.out[2] = KVb; P.obf[2] = 4;
        P.wt[3] = wt + (size_t)(12 + l)*HH;  P.bias[3] = bskip+ (size_t)l*H;  P.out[3] = XRp; P.obf[3] = 5;
        k_gemm<<<dim3(63, 16), 256, 0, stream>>>(xb, P);
        k_attn<<<NN/4, 256, 0, stream>>>(Qb, KVb, XRp, etab + (size_t)l*64*256, offa, spair,
                                         wbeta + (size_t)l*3*H, ln_g + (size_t)l*H,
                                         ln_b + (size_t)l*H, x, xb);
    }
    {
        GemmP P;
        P.wt[0] = wt + (size_t)16*HH; P.bias[0] = nullptr; P.out[0] = xs1; P.obf[0] = 2;
        P.wt[1] = wt + (size_t)17*HH; P.bias[1] = nullptr; P.out[1] = xd1; P.obf[1] = 2;
        P.wt[2] = P.wt[0]; P.bias[2] = nullptr; P.out[2] = xs1; P.obf[2] = 2;
        P.wt[3] = P.wt[0]; P.bias[3] = nullptr; P.out[3] = xs1; P.obf[3] = 2;
        k_gemm<<<dim3(63, 8), 256, 0, stream>>>(xb, P);
    }
    k_nodeout<<<63, 256, 0, stream>>>(xb, w32t, nob, (float*)d_out);
    k_edgemlp<<<NE/(4*EML), 256, 0, stream>>>(eprep, xs1, xd1, ctab,
                                              w2t, eb2, (float*)d_out + (size_t)NN*32);
}

// Round 12
// 460.068 us; speedup vs baseline: 1.0195x; 1.0195x over previous
//
#include <hip/hip_runtime.h>
#include <hip/hip_bf16.h>
#include <math.h>

#define NN 16000
#define NPAD 16128
#define NE 256000
#define H 192
#define RP 256           // padded row: 64 lanes * 4 (bytes for fp8 tables)
#define KVR 512          // fused K/V row: 64 lanes * 8 bytes (K dword + V dword)
#define NL 4
#define NBATCH 8
#define VEt 8
#define HH (H*H)
#define EML 16

typedef __hip_bfloat16 bf16;
typedef unsigned short u16;
typedef unsigned char u8;
typedef unsigned int u32;
typedef __attribute__((ext_vector_type(8))) short bfrag_t;
typedef __attribute__((ext_vector_type(4))) float facc_t;
typedef __attribute__((ext_vector_type(4))) float f4;
typedef __attribute__((ext_vector_type(2))) unsigned int u32x2;
typedef __attribute__((ext_vector_type(2))) float f2v;

__device__ __forceinline__ bf16 f2b(float v){ return __float2bfloat16(v); }
__device__ __forceinline__ int rfl(int v){ return __builtin_amdgcn_readfirstlane(v); }

// ---- fp8 e4m3fn software encode, RTNE (fallback) ----
__device__ __forceinline__ unsigned enc8sw(float x){
    unsigned u = __float_as_uint(x);
    unsigned s = (u >> 24) & 0x80u;
    float ax = fabsf(x);
    if(ax >= 448.f) return s | 0x7Eu;
    if(ax < 0.015625f){
        int q = (int)rintf(ax * 512.f);
        return s | (unsigned)q;
    }
    unsigned au = u & 0x7FFFFFFFu;
    unsigned lsb = (au >> 20) & 1u;
    au += 0x7FFFFu + lsb;
    unsigned E = (au >> 23) - 127u;
    unsigned M = (au >> 20) & 7u;
    if((int)E > 8) return s | 0x7Eu;
    return s | ((E + 7u) << 3) | M;
}
__device__ __forceinline__ unsigned enc8(float x){
#if __has_builtin(__builtin_amdgcn_cvt_pk_fp8_f32)
    return (u32)__builtin_amdgcn_cvt_pk_fp8_f32(x, x, 0, false) & 0xFFu;
#else
    return enc8sw(x);
#endif
}
template<int SEL>
__device__ __forceinline__ float dec8s(u32 w){
#if __has_builtin(__builtin_amdgcn_cvt_f32_fp8)
    return __builtin_amdgcn_cvt_f32_fp8((int)w, SEL);
#else
    unsigned v = (w >> (SEL*8)) & 0xFFu;
    unsigned e = (v >> 3) & 15u, m = v & 7u;
    float mag = e ? __builtin_ldexpf((float)(8u + m), (int)e - 10)
                  : __builtin_ldexpf((float)m, -9);
    return (v & 0x80u) ? -mag : mag;
#endif
}
// packed decode of bytes 0,1
__device__ __forceinline__ f2v dec8pk01(u32 w){
#if __has_builtin(__builtin_amdgcn_cvt_pk_f32_fp8)
    return __builtin_amdgcn_cvt_pk_f32_fp8((int)w, false);
#else
    f2v r; r.x = dec8s<0>(w); r.y = dec8s<1>(w); return r;
#endif
}
__device__ __forceinline__ float frcp(float x){
#if __has_builtin(__builtin_amdgcn_rcpf)
    return __builtin_amdgcn_rcpf(x);
#else
    return 1.f/x;
#endif
}

__global__ void k_sentinel(float* __restrict__ out, float v){ out[0] = v; }

// ---------------- prep0: {weight transpose | tvec MLP | zero cnt} ----------------
// blocks [0,160): transpose (20 mats x 8 slices); [160,168): tvec; [168,231): zero
__global__ void k_prep0(const float* __restrict__ wq, const float* __restrict__ wk,
                        const float* __restrict__ wv, const float* __restrict__ wsk,
                        const float* __restrict__ w1, const float* __restrict__ now,
                        const float* __restrict__ ew2, u16* __restrict__ wt,
                        const int* __restrict__ tg, const float* __restrict__ tw1,
                        const float* __restrict__ tb1, const float* __restrict__ tw2,
                        const float* __restrict__ tb2, float* __restrict__ tvec,
                        int* __restrict__ cnt){
    int blk = blockIdx.x;
    if(blk < 160){
        int mat = blk >> 3, ys = blk & 7;
        if(mat < 18){
            const float* src;
            if(mat < 4)       src = wq  + (size_t)mat*HH;
            else if(mat < 8)  src = wk  + (size_t)(mat-4)*HH;
            else if(mat < 12) src = wv  + (size_t)(mat-8)*HH;
            else if(mat < 16) src = wsk + (size_t)(mat-12)*HH;
            else              src = w1  + (size_t)(mat-16)*HH;
            u16* dst = wt + (size_t)mat*HH;
            const int slice = HH/8;
            int base = ys*slice;
            for(int i = base + threadIdx.x; i < base + slice; i += blockDim.x){
                int k = i / H, n = i % H;
                bf16 b = f2b(src[i]);
                dst[n*H + k] = *(u16*)&b;
            }
        } else if(mat == 18){
            u16* dst = wt + (size_t)18*HH;
            const int slice = (32*192)/8;
            int base = ys*slice;
            for(int i = base + threadIdx.x; i < base + slice; i += blockDim.x){
                int k = i >> 5, n = i & 31;
                bf16 b = f2b(now[i]);
                dst[n*192 + k] = *(u16*)&b;
            }
        } else {
            u16* dst = wt + (size_t)18*HH + 32*192;
            const int slice = (16*192)/8;
            int base = ys*slice;
            for(int i = base + threadIdx.x; i < base + slice; i += blockDim.x){
                int k = i >> 4, n = i & 15;
                float v = (n < 8) ? ew2[k*8 + n] : 0.f;
                bf16 b = f2b(v);
                dst[n*192 + k] = *(u16*)&b;
            }
        }
    } else if(blk < 168){
        int b = blk - 160, j = threadIdx.x;
        __shared__ float emb[H], h1[H];
        float t = (float)tg[b];
        if(j < 96){
            float fr = __expf(-logf(10000.0f) * (float)j / 96.0f);
            float ang = t * fr;
            emb[j]      = sinf(ang);
            emb[j + 96] = cosf(ang);
        }
        __syncthreads();
        if(j < H){
            float acc = tb1[j];
            for(int k = 0; k < H; k++) acc += emb[k] * tw1[k*H + j];
            h1[j] = acc / (1.f + __expf(-acc));
        }
        __syncthreads();
        if(j < H){
            float acc2 = tb2[j];
            for(int k = 0; k < H; k++) acc2 += h1[k] * tw2[k*H + j];
            tvec[b*H + j] = acc2;
        }
    } else {
        int i = (blk - 168)*256 + threadIdx.x;
        if(i < NN+1) cnt[i] = 0;
    }
}

// ---------------- prep1: {init_x | count | e/c-tables} ----------------
// blocks [0,12000): init_x; [12000,13000): count; [13000,13320): tabs
__global__ void k_prep1(const float* __restrict__ nemb, const float* __restrict__ memb,
                        const float* __restrict__ tvec, const int* __restrict__ ntype,
                        const int* __restrict__ emask, const int* __restrict__ nbatch,
                        float* __restrict__ x, u16* __restrict__ xb,
                        const int* __restrict__ edst, int* __restrict__ cnt,
                        const float* __restrict__ eemb, const float* __restrict__ we,
                        const float* __restrict__ w1, const float* __restrict__ b1,
                        u16* __restrict__ etab, u16* __restrict__ ctab){
    int blk = blockIdx.x;
    if(blk < 12000){
        int idx = blk*256 + threadIdx.x;
        int n = idx / H, c = idx % H;
        float v = nemb[(size_t)ntype[n]*H + c] + tvec[nbatch[n]*H + c]
                + memb[(size_t)emask[n]*H + c];
        x[idx] = v;
        bf16 b = f2b(v); xb[idx] = *(u16*)&b;
    } else if(blk < 13000){
        int e = (blk - 12000)*256 + threadIdx.x;
        atomicAdd(&cnt[edst[e]], 1);
    } else {
        int blk2 = blk - 13000;
        int c = threadIdx.x;
        __shared__ float a[H];
        if(blk2 < NL*64){
            int l = blk2 >> 6, idx = blk2 & 63, b = idx >> 3, et = idx & 7;
            if(c < H) a[c] = eemb[et*H + c] + tvec[b*H + c];
            __syncthreads();
            if(c < H){
                float acc = 0.f;
                const float* w = we + (size_t)l*HH;
                for(int k = 0; k < H; k++) acc += a[k] * w[k*H + c];
                bf16 bv = f2b(acc);
                etab[(size_t)blk2*256 + (c/3)*4 + (c%3)] = *(u16*)&bv;
            }
        } else {
            int idx = blk2 - NL*64, b = idx >> 3, et = idx & 7;
            if(c < H) a[c] = eemb[et*H + c] + tvec[b*H + c];
            __syncthreads();
            if(c < H){
                float acc = b1[c];
                for(int k = 0; k < H; k++){
                    acc += a[k]          * w1[(size_t)(2*H + k)*H + c];
                    acc += tvec[b*H + k] * w1[(size_t)(3*H + k)*H + c];
                }
                bf16 bv = f2b(acc);
                ctab[(size_t)idx*256 + (c/3)*4 + (c%3)] = *(u16*)&bv;
            }
        }
    }
}

__global__ __launch_bounds__(1024) void k_scan(const int* __restrict__ cnt,
                                               int* __restrict__ ofs, int* __restrict__ cur){
    __shared__ int wsum[16];
    __shared__ int carry_s;
    int tid = threadIdx.x, lane = tid & 63, w = tid >> 6;
    if(tid == 0) carry_s = 0;
    __syncthreads();
    for(int base = 0; base < NN; base += 1024){
        int idx = base + tid;
        int v = (idx < NN) ? cnt[idx] : 0;
        int sc = v;
        #pragma unroll
        for(int o = 1; o < 64; o <<= 1){
            int t = __shfl_up(sc, o);
            if(lane >= o) sc += t;
        }
        if(lane == 63) wsum[w] = sc;
        __syncthreads();
        if(w == 0){
            int ws = (lane < 16) ? wsum[lane] : 0;
            #pragma unroll
            for(int o = 1; o < 16; o <<= 1){
                int t = __shfl_up(ws, o);
                if(lane >= o) ws += t;
            }
            if(lane < 16) wsum[lane] = ws;
        }
        __syncthreads();
        int wbase = (w > 0) ? wsum[w-1] : 0;
        int c = carry_s;
        int excl = c + wbase + sc - v;
        if(idx < NN){ ofs[idx] = excl; cur[idx] = excl; }
        __syncthreads();
        if(tid == 0) carry_s = c + wsum[15];
        __syncthreads();
    }
    if(threadIdx.x == 0) ofs[NN] = carry_s;
}
// spair: sorted-by-dst {s*KVR, ct*KVR}; eprep: per-original-edge {s*RP, d*RP, ct*KVR, 0}
__global__ void k_scatter(const int* __restrict__ esrc, const int* __restrict__ edst,
                          const int* __restrict__ etype, const int* __restrict__ nbatch,
                          int* __restrict__ cur, int2* __restrict__ spair, int4* __restrict__ eprep){
    int e = blockIdx.x*blockDim.x + threadIdx.x;
    if(e >= NE) return;
    int s = esrc[e], d = edst[e];
    int ct = (nbatch[s]*VEt + etype[e])*KVR;
    int pos = atomicAdd(&cur[d], 1);
    int2 se; se.x = s*KVR; se.y = ct;
    spair[pos] = se;
    eprep[e] = make_int4(s*RP, d*RP, ct, 0);
}

// ---------------- MFMA GEMM ----------------
// obf: 0 = fp32 row-H; 2 = fp8 RP-row; 3 = fp8 KV-row K-half; 4 = fp8 KV-row V-half;
//      5 = bf16 packed 512B rows ([c0|c1][c2|pad] per lane)
struct GemmP {
    const u16* wt[4];
    const float* bias[4];
    void* out[4];
    int obf[4];
};
__global__ __launch_bounds__(256) void k_gemm(const u16* __restrict__ A, GemmP P){
    int oi = blockIdx.y / 3, nt = blockIdx.y % 3;
    const u16* Wt = P.wt[oi];
    const float* bias = P.bias[oi];
    int wave = rfl(threadIdx.x >> 6), lane = threadIdx.x & 63;
    int quad = lane >> 4, l16 = lane & 15;
    int m0 = blockIdx.x*256 + wave*64;
    int n0 = nt*64;
    facc_t acc[4][4];
    #pragma unroll
    for(int i = 0; i < 4; i++)
        #pragma unroll
        for(int j = 0; j < 4; j++){ acc[i][j][0]=0.f; acc[i][j][1]=0.f; acc[i][j][2]=0.f; acc[i][j][3]=0.f; }
    #pragma unroll
    for(int kc = 0; kc < 6; kc++){
        int kb = kc*32 + quad*8;
        bfrag_t af[4], bg[4];
        #pragma unroll
        for(int i = 0; i < 4; i++) af[i] = *(const bfrag_t*)(A  + (size_t)(m0 + i*16 + l16)*H + kb);
        #pragma unroll
        for(int j = 0; j < 4; j++) bg[j] = *(const bfrag_t*)(Wt + (size_t)(n0 + j*16 + l16)*H + kb);
        #pragma unroll
        for(int i = 0; i < 4; i++)
            #pragma unroll
            for(int j = 0; j < 4; j++)
                acc[i][j] = __builtin_amdgcn_mfma_f32_16x16x32_bf16(af[i], bg[j], acc[i][j], 0, 0, 0);
    }
    float bv[4];
    #pragma unroll
    for(int j = 0; j < 4; j++) bv[j] = bias ? bias[n0 + j*16 + l16] : 0.f;
    int mode = P.obf[oi];
    if(mode == 5){
        u16* outp = (u16*)P.out[oi];
        int hoff[4];
        #pragma unroll
        for(int j = 0; j < 4; j++){
            int c = n0 + j*16 + l16;
            hoff[j] = (c/3)*4 + (c%3);
        }
        #pragma unroll
        for(int i = 0; i < 4; i++){
            int rb = m0 + i*16 + quad*4;
            #pragma unroll
            for(int r = 0; r < 4; r++){
                int row = rb + r;
                if(row < NN){
                    #pragma unroll
                    for(int j = 0; j < 4; j++){
                        bf16 b = f2b(acc[i][j][r] + bv[j]);
                        outp[(size_t)row*256 + hoff[j]] = *(u16*)&b;
                    }
                }
            }
        }
    } else if(mode != 0){
        u8* out = (u8*)P.out[oi];
        int rstride = (mode == 2) ? RP : KVR;
        int mult    = (mode == 2) ? 4  : 8;
        int koff    = (mode == 4) ? 4  : 0;
        int byteoff[4];
        #pragma unroll
        for(int j = 0; j < 4; j++){
            int c = n0 + j*16 + l16;
            byteoff[j] = (c/3)*mult + (c%3) + koff;
        }
        #pragma unroll
        for(int i = 0; i < 4; i++){
            int rb = m0 + i*16 + quad*4;
            #pragma unroll
            for(int r = 0; r < 4; r++){
                int row = rb + r;
                if(row < NN){
                    #pragma unroll
                    for(int j = 0; j < 4; j++)
                        out[(size_t)row*rstride + byteoff[j]] = (u8)enc8(acc[i][j][r] + bv[j]);
                }
            }
        }
    } else {
        float* out = (float*)P.out[oi];
        #pragma unroll
        for(int i = 0; i < 4; i++){
            int rb = m0 + i*16 + quad*4;
            #pragma unroll
            for(int r = 0; r < 4; r++){
                int row = rb + r;
                if(row < NN){
                    #pragma unroll
                    for(int j = 0; j < 4; j++)
                        out[(size_t)row*H + n0 + j*16 + l16] = acc[i][j][r] + bv[j];
                }
            }
        }
    }
}

// ---------------- fused attention + gate + LN; pipelined, packed decode ----------------
// Qb: bf16 packed 512B rows; KVb: 512B fp8 rows; etab: bf16 512B rows
__global__ __launch_bounds__(256) void k_attn(
    const u8* __restrict__ Qb, const u8* __restrict__ KVb,
    const float* __restrict__ XR,
    const u16* __restrict__ etab, const int* __restrict__ ofs,
    const int2* __restrict__ spair,
    const float* __restrict__ wb, const float* __restrict__ lng, const float* __restrict__ lnb,
    float* __restrict__ x, u16* __restrict__ xb)
{
    int wv = rfl(threadIdx.x >> 6);
    int n = blockIdx.x*4 + wv;
    int lane = threadIdx.x & 63;
    int lane8 = lane*8;
    int ch = lane*3;
    size_t base = (size_t)n*H + ch;
    const float scale = 0.14433756729740646f;   // 1/sqrt(48)
    u32x2 qw = *(const u32x2*)(Qb + (size_t)n*512 + lane8);
    float q0 = __uint_as_float(qw.x << 16);
    float q1 = __uint_as_float(qw.x & 0xffff0000u);
    float q2 = __uint_as_float(qw.y << 16);
    int p0 = ofs[n], p1 = ofs[n+1];
    float lac[4]  = {0.f,0.f,0.f,0.f};
    float ac0[4]  = {0.f,0.f,0.f,0.f};
    float ac1[4]  = {0.f,0.f,0.f,0.f};
    float ac2[4]  = {0.f,0.f,0.f,0.f};
    const u8* etb = (const u8*)etab;
    int p = p0;
    u32x2 kvc[4], ewc[4];
    bool have = (p + 3 < p1);
    if(have){
        #pragma unroll
        for(int t = 0; t < 4; t++){
            int2 se = spair[p+t];
            kvc[t] = *(const u32x2*)(KVb + se.x + lane8);
            ewc[t] = *(const u32x2*)(etb + se.y + lane8);
        }
    }
    while(have){
        int pn = p + 4;
        bool more = (pn + 3 < p1);
        u32x2 kvn[4], ewn[4];
        if(more){
            #pragma unroll
            for(int t = 0; t < 4; t++){
                int2 se = spair[pn+t];
                kvn[t] = *(const u32x2*)(KVb + se.x + lane8);
                ewn[t] = *(const u32x2*)(etb + se.y + lane8);
            }
        }
        float e0[4], e1[4], e2[4], tt[4];
        #pragma unroll
        for(int t = 0; t < 4; t++){
            e0[t] = __uint_as_float(ewc[t].x << 16);
            e1[t] = __uint_as_float(ewc[t].x & 0xffff0000u);
            e2[t] = __uint_as_float(ewc[t].y << 16);
            f2v k01 = dec8pk01(kvc[t].x);
            float k2 = dec8s<2>(kvc[t].x);
            tt[t] = q0*(k01.x+e0[t]) + q1*(k01.y+e1[t]) + q2*(k2+e2[t]);
        }
        #pragma unroll
        for(int o = 1; o <= 8; o <<= 1){
            #pragma unroll
            for(int t = 0; t < 4; t++) tt[t] += __shfl_xor(tt[t], o);
        }
        #pragma unroll
        for(int t = 0; t < 4; t++){
            float sc = fminf(fmaxf(tt[t]*scale, -60.f), 60.f);
            float pw = __expf(sc);
            f2v v01 = dec8pk01(kvc[t].y);
            float v2 = dec8s<2>(kvc[t].y);
            lac[t] += pw;
            ac0[t] += pw*(v01.x+e0[t]);
            ac1[t] += pw*(v01.y+e1[t]);
            ac2[t] += pw*(v2+e2[t]);
        }
        if(more){
            #pragma unroll
            for(int t = 0; t < 4; t++){ kvc[t] = kvn[t]; ewc[t] = ewn[t]; }
        }
        p = pn;
        have = more;
    }
    for(; p < p1; p++){
        int soA = spair[p].x, eoA = spair[p].y;
        u32x2 kvA = *(const u32x2*)(KVb + soA + lane8);
        u32x2 ewA = *(const u32x2*)(etb + eoA + lane8);
        float e0A = __uint_as_float(ewA.x << 16);
        float e1A = __uint_as_float(ewA.x & 0xffff0000u);
        float e2A = __uint_as_float(ewA.y << 16);
        f2v k01 = dec8pk01(kvA.x);
        float k2 = dec8s<2>(kvA.x);
        float tA = q0*(k01.x+e0A) + q1*(k01.y+e1A) + q2*(k2+e2A);
        tA += __shfl_xor(tA,1); tA += __shfl_xor(tA,2); tA += __shfl_xor(tA,4); tA += __shfl_xor(tA,8);
        float sc = fminf(fmaxf(tA*scale, -60.f), 60.f);
        float pw = __expf(sc);
        f2v v01 = dec8pk01(kvA.y);
        float v2 = dec8s<2>(kvA.y);
        lac[0] += pw;
        ac0[0] += pw*(v01.x+e0A);
        ac1[0] += pw*(v01.y+e1A);
        ac2[0] += pw*(v2+e2A);
    }
    float l  = (lac[0]+lac[1]) + (lac[2]+lac[3]);
    float a0 = (ac0[0]+ac0[1]) + (ac0[2]+ac0[3]);
    float a1 = (ac1[0]+ac1[1]) + (ac1[2]+ac1[3]);
    float a2 = (ac2[0]+ac2[1]) + (ac2[2]+ac2[3]);
    float inv = (p1 > p0) ? 1.f/l : 0.f;
    float o0 = a0*inv, o1 = a1*inv, o2 = a2*inv;
    float xr0 = XR[base], xr1 = XR[base+1], xr2 = XR[base+2];
    float sd = o0*wb[ch]  + o1*wb[ch+1]  + o2*wb[ch+2]
             + xr0*wb[H+ch] + xr1*wb[H+ch+1] + xr2*wb[H+ch+2]
             + (o0-xr0)*wb[2*H+ch] + (o1-xr1)*wb[2*H+ch+1] + (o2-xr2)*wb[2*H+ch+2];
    sd += __shfl_xor(sd,1); sd += __shfl_xor(sd,2); sd += __shfl_xor(sd,4);
    sd += __shfl_xor(sd,8); sd += __shfl_xor(sd,16); sd += __shfl_xor(sd,32);
    float beta = 1.f/(1.f + __expf(-sd));
    float h0 = beta*xr0 + (1.f-beta)*o0;
    float h1 = beta*xr1 + (1.f-beta)*o1;
    float h2 = beta*xr2 + (1.f-beta)*o2;
    float y0 = x[base] + h0, y1 = x[base+1] + h1, y2 = x[base+2] + h2;
    float s3 = y0 + y1 + y2;
    float q3 = y0*y0 + y1*y1 + y2*y2;
    #pragma unroll
    for(int o = 1; o <= 32; o <<= 1){
        s3 += __shfl_xor(s3, o);
        q3 += __shfl_xor(q3, o);
    }
    float mean = s3 * (1.f/H);
    float var = fmaxf(q3*(1.f/H) - mean*mean, 0.f);
    float rs = rsqrtf(var + 1e-5f);
    float d0 = y0-mean, d1 = y1-mean, d2 = y2-mean;
    float z0 = d0*rs*lng[ch]   + lnb[ch];
    float z1 = d1*rs*lng[ch+1] + lnb[ch+1];
    float z2 = d2*rs*lng[ch+2] + lnb[ch+2];
    x[base] = z0; x[base+1] = z1; x[base+2] = z2;
    bf16 t0 = f2b(z0), t1 = f2b(z1), t2 = f2b(z2);
    xb[base] = *(u16*)&t0; xb[base+1] = *(u16*)&t1; xb[base+2] = *(u16*)&t2;
}

// ---------------- node logits: MFMA (M=16128, N=32, K=192), A = xb bf16 ----------------
__global__ __launch_bounds__(256) void k_nodeout(const u16* __restrict__ A, const u16* __restrict__ Wt,
                                                 const float* __restrict__ b, float* __restrict__ out){
    int wave = rfl(threadIdx.x >> 6), lane = threadIdx.x & 63;
    int quad = lane >> 4, l16 = lane & 15;
    int m0 = blockIdx.x*256 + wave*64;
    facc_t acc[4][2];
    #pragma unroll
    for(int i = 0; i < 4; i++)
        #pragma unroll
        for(int j = 0; j < 2; j++){ acc[i][j][0]=0.f; acc[i][j][1]=0.f; acc[i][j][2]=0.f; acc[i][j][3]=0.f; }
    #pragma unroll
    for(int kc = 0; kc < 6; kc++){
        int kb = kc*32 + quad*8;
        bfrag_t af[4], bg[2];
        #pragma unroll
        for(int i = 0; i < 4; i++) af[i] = *(const bfrag_t*)(A  + (size_t)(m0 + i*16 + l16)*H + kb);
        #pragma unroll
        for(int j = 0; j < 2; j++) bg[j] = *(const bfrag_t*)(Wt + (size_t)(j*16 + l16)*H + kb);
        #pragma unroll
        for(int i = 0; i < 4; i++)
            #pragma unroll
            for(int j = 0; j < 2; j++)
                acc[i][j] = __builtin_amdgcn_mfma_f32_16x16x32_bf16(af[i], bg[j], acc[i][j], 0, 0, 0);
    }
    float bv[2];
    #pragma unroll
    for(int j = 0; j < 2; j++) bv[j] = b[j*16 + l16];
    #pragma unroll
    for(int i = 0; i < 4; i++){
        int rb = m0 + i*16 + quad*4;
        #pragma unroll
        for(int r = 0; r < 4; r++){
            int row = rb + r;
            if(row < NN){
                #pragma unroll
                for(int j = 0; j < 2; j++)
                    out[(size_t)row*32 + j*16 + l16] = acc[i][j][r] + bv[j];
            }
        }
    }
}

// ---------------- edge logits: eprep-driven gather+silu -> LDS bf16 -> MFMA ----------------
__global__ __launch_bounds__(256) void k_edgemlp(
    const int4* __restrict__ eprep,
    const u8* __restrict__ xs1, const u8* __restrict__ xd1, const u16* __restrict__ ctab,
    const u16* __restrict__ w2t, const float* __restrict__ b2p, float* __restrict__ out)
{
    __shared__ u16 hbuf[4][16][200];    // [wave][edge][192 bf16 + 8 pad]
    int wave = rfl(threadIdx.x >> 6);
    int lane = threadIdx.x & 63;
    int lane8 = lane*8;
    int l16 = lane & 15, quad = lane >> 4;
    int wid = blockIdx.x*4 + wave;
    int e0 = wid*EML;
    const u8* ctb = (const u8*)ctab;
    bfrag_t bg[6];
    #pragma unroll
    for(int kc = 0; kc < 6; kc++)
        bg[kc] = *(const bfrag_t*)(w2t + (size_t)l16*192 + kc*32 + quad*8);
    for(int eb = 0; eb < EML; eb += 2){
        int4 epX = eprep[e0 + eb];
        int4 epY = eprep[e0 + eb + 1];
        u32 awX = *(const u32*)(xs1 + epX.x + lane*4);
        u32 awY = *(const u32*)(xs1 + epY.x + lane*4);
        u32 bwX = *(const u32*)(xd1 + epX.y + lane*4);
        u32 bwY = *(const u32*)(xd1 + epY.y + lane*4);
        u32x2 cwX = *(const u32x2*)(ctb + epX.z + lane8);
        u32x2 cwY = *(const u32x2*)(ctb + epY.z + lane8);
        float cfX0 = __uint_as_float(cwX.x << 16);
        float cfX1 = __uint_as_float(cwX.x & 0xffff0000u);
        float cfX2 = __uint_as_float(cwX.y << 16);
        float cfY0 = __uint_as_float(cwY.x << 16);
        float cfY1 = __uint_as_float(cwY.x & 0xffff0000u);
        float cfY2 = __uint_as_float(cwY.y << 16);
        f2v aX = dec8pk01(awX), bX = dec8pk01(bwX);
        f2v aY = dec8pk01(awY), bY = dec8pk01(bwY);
        float aX2 = dec8s<2>(awX), bX2 = dec8s<2>(bwX);
        float aY2 = dec8s<2>(awY), bY2 = dec8s<2>(bwY);
        float hX0, hX1, hX2, hY0, hY1, hY2;
        { float v = aX.x+bX.x+cfX0; hX0 = v*frcp(1.f+__expf(-v)); }
        { float v = aX.y+bX.y+cfX1; hX1 = v*frcp(1.f+__expf(-v)); }
        { float v = aX2 +bX2 +cfX2; hX2 = v*frcp(1.f+__expf(-v)); }
        { float v = aY.x+bY.x+cfY0; hY0 = v*frcp(1.f+__expf(-v)); }
        { float v = aY.y+bY.y+cfY1; hY1 = v*frcp(1.f+__expf(-v)); }
        { float v = aY2 +bY2 +cfY2; hY2 = v*frcp(1.f+__expf(-v)); }
        u16* rowX = &hbuf[wave][eb][0];
        u16* rowY = &hbuf[wave][eb+1][0];
        bf16 x0 = f2b(hX0), x1 = f2b(hX1), x2 = f2b(hX2);
        bf16 y0 = f2b(hY0), y1 = f2b(hY1), y2 = f2b(hY2);
        rowX[lane*3+0] = *(u16*)&x0; rowX[lane*3+1] = *(u16*)&x1; rowX[lane*3+2] = *(u16*)&x2;
        rowY[lane*3+0] = *(u16*)&y0; rowY[lane*3+1] = *(u16*)&y1; rowY[lane*3+2] = *(u16*)&y2;
    }
    __syncthreads();
    facc_t acc;
    acc[0]=0.f; acc[1]=0.f; acc[2]=0.f; acc[3]=0.f;
    #pragma unroll
    for(int kc = 0; kc < 6; kc++){
        bfrag_t af = *(const bfrag_t*)&hbuf[wave][l16][kc*32 + quad*8];
        acc = __builtin_amdgcn_mfma_f32_16x16x32_bf16(af, bg[kc], acc, 0, 0, 0);
    }
    if(l16 < 8){
        float bo = b2p[l16];
        #pragma unroll
        for(int r = 0; r < 4; r++){
            int e = e0 + quad*4 + r;
            out[(size_t)e*8 + l16] = acc[r] + bo;
        }
    }
}

extern "C" void kernel_launch(void* const* d_in, const int* in_sizes, int n_in,
                              void* d_out, int out_size, void* d_ws, size_t ws_size,
                              hipStream_t stream)
{
    {
        int bad = -1;
        if(n_in != 31) bad = 100;
        else {
            const int chk_idx[9] = {0, 7, 16, 21, 23, 26, 27, 29, 30};
            const int chk_sz [9] = {32*H, NL*HH, NL*3*H, 4*HH, H*8, NE, 2*NE, NN, NBATCH};
            for(int i = 0; i < 9; i++) if(in_sizes[chk_idx[i]] != chk_sz[i]){ bad = chk_idx[i]; break; }
        }
        if(bad >= 0){ k_sentinel<<<1,1,0,stream>>>((float*)d_out, 20000.f + 256.f*bad); return; }
        if(out_size != NN*32 + NE*8){ k_sentinel<<<1,1,0,stream>>>((float*)d_out, 30000.f); return; }
    }

    const float* node_emb = (const float*)d_in[0];
    const float* edge_emb = (const float*)d_in[1];
    const float* time_w1  = (const float*)d_in[2];
    const float* time_b1  = (const float*)d_in[3];
    const float* time_w2  = (const float*)d_in[4];
    const float* time_b2  = (const float*)d_in[5];
    const float* mask_emb = (const float*)d_in[6];
    const float* wq       = (const float*)d_in[7];
    const float* bq       = (const float*)d_in[8];
    const float* wk       = (const float*)d_in[9];
    const float* bk       = (const float*)d_in[10];
    const float* wv       = (const float*)d_in[11];
    const float* bv       = (const float*)d_in[12];
    const float* we       = (const float*)d_in[13];
    const float* wskip    = (const float*)d_in[14];
    const float* bskip    = (const float*)d_in[15];
    const float* wbeta    = (const float*)d_in[16];
    const float* ln_g     = (const float*)d_in[17];
    const float* ln_b     = (const float*)d_in[18];
    const float* now      = (const float*)d_in[19];
    const float* nob      = (const float*)d_in[20];
    const float* ew1      = (const float*)d_in[21];
    const float* eb1      = (const float*)d_in[22];
    const float* ew2      = (const float*)d_in[23];
    const float* eb2      = (const float*)d_in[24];
    const int* node_type  = (const int*)d_in[25];
    const int* edge_type  = (const int*)d_in[26];
    const int* edge_index = (const int*)d_in[27];
    const int* edit_mask  = (const int*)d_in[28];
    const int* node_batch = (const int*)d_in[29];
    const int* t_graph    = (const int*)d_in[30];
    const int* esrc = edge_index;
    const int* edst = edge_index + NE;

    char* wsb = (char*)d_ws;
    size_t off = 0;
    auto take = [&](size_t bytes) -> char* {
        char* r = wsb + off;
        off += (bytes + 255) & ~(size_t)255;
        return r;
    };
    float* tvec = (float*)take((size_t)NBATCH*H*4);
    float* x    = (float*)take((size_t)NN*H*4);
    u16*   xb   = (u16*)  take((size_t)NPAD*H*2);
    u8*    Qb   = (u8*)   take((size_t)NN*512);
    u8*    KVb  = (u8*)   take((size_t)NN*KVR);
    float* XR   = (float*)take((size_t)NN*H*4);
    u8*    xs1  = (u8*)   take((size_t)NN*RP);
    u8*    xd1  = (u8*)   take((size_t)NN*RP);
    u16*   etab = (u16*)  take((size_t)NL*64*KVR);
    u16*   ctab = (u16*)  take((size_t)64*KVR);
    u16*   wt   = (u16*)  take((size_t)(18*HH + 32*192 + 16*192)*2);
    int* cnt    = (int*)  take((size_t)(NN+1)*4);
    int* offa   = (int*)  take((size_t)(NN+1)*4);
    int* cur    = (int*)  take((size_t)(NN+1)*4);
    int2* spair = (int2*) take((size_t)NE*8);
    int4* eprep = (int4*) take((size_t)NE*16);

    if(ws_size < off){
        k_sentinel<<<1,1,0,stream>>>((float*)d_out, 10000.f + (float)(ws_size >> 20));
        return;
    }

    u16* w32t = wt + (size_t)18*HH;          // [32][192] bf16 (node_out_w^T)
    u16* w2t  = w32t + 32*192;               // [16][192] bf16 (edge_w2^T, zero-padded)

    k_prep0<<<231, 256, 0, stream>>>(wq, wk, wv, wskip, ew1, now, ew2, wt,
                                     t_graph, time_w1, time_b1, time_w2, time_b2, tvec, cnt);
    k_prep1<<<13320, 256, 0, stream>>>(node_emb, mask_emb, tvec, node_type, edit_mask, node_batch,
                                       x, xb, edst, cnt, edge_emb, we, ew1, eb1, etab, ctab);
    k_scan<<<1, 1024, 0, stream>>>(cnt, offa, cur);
    k_scatter<<<NE/256, 256, 0, stream>>>(esrc, edst, edge_type, node_batch, cur, spair, eprep);

    for(int l = 0; l < NL; l++){
        GemmP P;
        P.wt[0] = wt + (size_t)(0  + l)*HH;  P.bias[0] = bq   + (size_t)l*H;  P.out[0] = Qb;  P.obf[0] = 5;
        P.wt[1] = wt + (size_t)(4  + l)*HH;  P.bias[1] = bk   + (size_t)l*H;  P.out[1] = KVb; P.obf[1] = 3;
        P.wt[2] = wt + (size_t)(8  + l)*HH;  P.bias[2] = bv   + (size_t)l*H;  P.out[2] = KVb; P.obf[2] = 4;
        P.wt[3] = wt + (size_t)(12 + l)*HH;  P.bias[3] = bskip+ (size_t)l*H;  P.out[3] = XR;  P.obf[3] = 0;
        k_gemm<<<dim3(63, 12), 256, 0, stream>>>(xb, P);
        k_attn<<<NN/4, 256, 0, stream>>>(Qb, KVb, XR, etab + (size_t)l*64*256, offa, spair,
                                         wbeta + (size_t)l*3*H, ln_g + (size_t)l*H,
                                         ln_b + (size_t)l*H, x, xb);
    }
    {
        GemmP P;
        P.wt[0] = wt + (size_t)16*HH; P.bias[0] = nullptr; P.out[0] = xs1; P.obf[0] = 2;
        P.wt[1] = wt + (size_t)17*HH; P.bias[1] = nullptr; P.out[1] = xd1; P.obf[1] = 2;
        P.wt[2] = P.wt[0]; P.bias[2] = nullptr; P.out[2] = xs1; P.obf[2] = 2;
        P.wt[3] = P.wt[0]; P.bias[3] = nullptr; P.out[3] = xs1; P.obf[3] = 2;
        k_gemm<<<dim3(63, 6), 256, 0, stream>>>(xb, P);
    }
    k_nodeout<<<63, 256, 0, stream>>>(xb, w32t, nob, (float*)d_out);
    k_edgemlp<<<NE/(4*EML), 256, 0, stream>>>(eprep, xs1, xd1, ctab,
                                              w2t, eb2, (float*)d_out + (size_t)NN*32);
}

// Round 13
// 454.158 us; speedup vs baseline: 1.0327x; 1.0130x over previous
//
#include <hip/hip_runtime.h>
#include <hip/hip_bf16.h>
#include <math.h>

#define NN 16000
#define NPAD 16128
#define NE 256000
#define H 192
#define RP 256           // padded row: 64 lanes * 4 (bytes for fp8 tables)
#define KVR 512          // fused K/V row: 64 lanes * 8 bytes (K dword + V dword)
#define NL 4
#define NBATCH 8
#define VEt 8
#define HH (H*H)
#define EML 16

typedef __hip_bfloat16 bf16;
typedef unsigned short u16;
typedef unsigned char u8;
typedef unsigned int u32;
typedef __attribute__((ext_vector_type(8))) short bfrag_t;
typedef __attribute__((ext_vector_type(4))) float facc_t;
typedef __attribute__((ext_vector_type(4))) float f4;
typedef __attribute__((ext_vector_type(2))) unsigned int u32x2;
typedef __attribute__((ext_vector_type(2))) float f2v;

__device__ __forceinline__ bf16 f2b(float v){ return __float2bfloat16(v); }
__device__ __forceinline__ int rfl(int v){ return __builtin_amdgcn_readfirstlane(v); }

// ---- fp8 e4m3fn software encode, RTNE (fallback) ----
__device__ __forceinline__ unsigned enc8sw(float x){
    unsigned u = __float_as_uint(x);
    unsigned s = (u >> 24) & 0x80u;
    float ax = fabsf(x);
    if(ax >= 448.f) return s | 0x7Eu;
    if(ax < 0.015625f){
        int q = (int)rintf(ax * 512.f);
        return s | (unsigned)q;
    }
    unsigned au = u & 0x7FFFFFFFu;
    unsigned lsb = (au >> 20) & 1u;
    au += 0x7FFFFu + lsb;
    unsigned E = (au >> 23) - 127u;
    unsigned M = (au >> 20) & 7u;
    if((int)E > 8) return s | 0x7Eu;
    return s | ((E + 7u) << 3) | M;
}
__device__ __forceinline__ unsigned enc8(float x){
#if __has_builtin(__builtin_amdgcn_cvt_pk_fp8_f32)
    return (u32)__builtin_amdgcn_cvt_pk_fp8_f32(x, x, 0, false) & 0xFFu;
#else
    return enc8sw(x);
#endif
}
template<int SEL>
__device__ __forceinline__ float dec8s(u32 w){
#if __has_builtin(__builtin_amdgcn_cvt_f32_fp8)
    return __builtin_amdgcn_cvt_f32_fp8((int)w, SEL);
#else
    unsigned v = (w >> (SEL*8)) & 0xFFu;
    unsigned e = (v >> 3) & 15u, m = v & 7u;
    float mag = e ? __builtin_ldexpf((float)(8u + m), (int)e - 10)
                  : __builtin_ldexpf((float)m, -9);
    return (v & 0x80u) ? -mag : mag;
#endif
}
// packed decode of bytes 0,1
__device__ __forceinline__ f2v dec8pk01(u32 w){
#if __has_builtin(__builtin_amdgcn_cvt_pk_f32_fp8)
    return __builtin_amdgcn_cvt_pk_f32_fp8((int)w, false);
#else
    f2v r; r.x = dec8s<0>(w); r.y = dec8s<1>(w); return r;
#endif
}
__device__ __forceinline__ float frcp(float x){
#if __has_builtin(__builtin_amdgcn_rcpf)
    return __builtin_amdgcn_rcpf(x);
#else
    return 1.f/x;
#endif
}

__global__ void k_sentinel(float* __restrict__ out, float v){ out[0] = v; }

// ---------------- prep0: {weight transpose | tvec MLP | zero cnt} ----------------
// blocks [0,160): transpose (20 mats x 8 slices); [160,168): tvec; [168,231): zero
__global__ void k_prep0(const float* __restrict__ wq, const float* __restrict__ wk,
                        const float* __restrict__ wv, const float* __restrict__ wsk,
                        const float* __restrict__ w1, const float* __restrict__ now,
                        const float* __restrict__ ew2, u16* __restrict__ wt,
                        const int* __restrict__ tg, const float* __restrict__ tw1,
                        const float* __restrict__ tb1, const float* __restrict__ tw2,
                        const float* __restrict__ tb2, float* __restrict__ tvec,
                        int* __restrict__ cnt){
    int blk = blockIdx.x;
    if(blk < 160){
        int mat = blk >> 3, ys = blk & 7;
        if(mat < 18){
            const float* src;
            if(mat < 4)       src = wq  + (size_t)mat*HH;
            else if(mat < 8)  src = wk  + (size_t)(mat-4)*HH;
            else if(mat < 12) src = wv  + (size_t)(mat-8)*HH;
            else if(mat < 16) src = wsk + (size_t)(mat-12)*HH;
            else              src = w1  + (size_t)(mat-16)*HH;
            u16* dst = wt + (size_t)mat*HH;
            const int slice = HH/8;
            int base = ys*slice;
            for(int i = base + threadIdx.x; i < base + slice; i += blockDim.x){
                int k = i / H, n = i % H;
                bf16 b = f2b(src[i]);
                dst[n*H + k] = *(u16*)&b;
            }
        } else if(mat == 18){
            u16* dst = wt + (size_t)18*HH;
            const int slice = (32*192)/8;
            int base = ys*slice;
            for(int i = base + threadIdx.x; i < base + slice; i += blockDim.x){
                int k = i >> 5, n = i & 31;
                bf16 b = f2b(now[i]);
                dst[n*192 + k] = *(u16*)&b;
            }
        } else {
            u16* dst = wt + (size_t)18*HH + 32*192;
            const int slice = (16*192)/8;
            int base = ys*slice;
            for(int i = base + threadIdx.x; i < base + slice; i += blockDim.x){
                int k = i >> 4, n = i & 15;
                float v = (n < 8) ? ew2[k*8 + n] : 0.f;
                bf16 b = f2b(v);
                dst[n*192 + k] = *(u16*)&b;
            }
        }
    } else if(blk < 168){
        int b = blk - 160, j = threadIdx.x;
        __shared__ float emb[H], h1[H];
        float t = (float)tg[b];
        if(j < 96){
            float fr = __expf(-logf(10000.0f) * (float)j / 96.0f);
            float ang = t * fr;
            emb[j]      = sinf(ang);
            emb[j + 96] = cosf(ang);
        }
        __syncthreads();
        if(j < H){
            float acc = tb1[j];
            for(int k = 0; k < H; k++) acc += emb[k] * tw1[k*H + j];
            h1[j] = acc / (1.f + __expf(-acc));
        }
        __syncthreads();
        if(j < H){
            float acc2 = tb2[j];
            for(int k = 0; k < H; k++) acc2 += h1[k] * tw2[k*H + j];
            tvec[b*H + j] = acc2;
        }
    } else {
        int i = (blk - 168)*256 + threadIdx.x;
        if(i < NN+1) cnt[i] = 0;
    }
}

// ---------------- prep1: {init_x | count | e/c-tables} ----------------
// blocks [0,12000): init_x; [12000,13000): count; [13000,13320): tabs
__global__ void k_prep1(const float* __restrict__ nemb, const float* __restrict__ memb,
                        const float* __restrict__ tvec, const int* __restrict__ ntype,
                        const int* __restrict__ emask, const int* __restrict__ nbatch,
                        float* __restrict__ x, u16* __restrict__ xb,
                        const int* __restrict__ edst, int* __restrict__ cnt,
                        const float* __restrict__ eemb, const float* __restrict__ we,
                        const float* __restrict__ w1, const float* __restrict__ b1,
                        u16* __restrict__ etab, u16* __restrict__ ctab){
    int blk = blockIdx.x;
    if(blk < 12000){
        int idx = blk*256 + threadIdx.x;
        int n = idx / H, c = idx % H;
        float v = nemb[(size_t)ntype[n]*H + c] + tvec[nbatch[n]*H + c]
                + memb[(size_t)emask[n]*H + c];
        x[idx] = v;
        bf16 b = f2b(v); xb[idx] = *(u16*)&b;
    } else if(blk < 13000){
        int e = (blk - 12000)*256 + threadIdx.x;
        atomicAdd(&cnt[edst[e]], 1);
    } else {
        int blk2 = blk - 13000;
        int c = threadIdx.x;
        __shared__ float a[H];
        if(blk2 < NL*64){
            int l = blk2 >> 6, idx = blk2 & 63, b = idx >> 3, et = idx & 7;
            if(c < H) a[c] = eemb[et*H + c] + tvec[b*H + c];
            __syncthreads();
            if(c < H){
                float acc = 0.f;
                const float* w = we + (size_t)l*HH;
                for(int k = 0; k < H; k++) acc += a[k] * w[k*H + c];
                bf16 bv = f2b(acc);
                etab[(size_t)blk2*256 + (c/3)*4 + (c%3)] = *(u16*)&bv;
            }
        } else {
            int idx = blk2 - NL*64, b = idx >> 3, et = idx & 7;
            if(c < H) a[c] = eemb[et*H + c] + tvec[b*H + c];
            __syncthreads();
            if(c < H){
                float acc = b1[c];
                for(int k = 0; k < H; k++){
                    acc += a[k]          * w1[(size_t)(2*H + k)*H + c];
                    acc += tvec[b*H + k] * w1[(size_t)(3*H + k)*H + c];
                }
                bf16 bv = f2b(acc);
                ctab[(size_t)idx*256 + (c/3)*4 + (c%3)] = *(u16*)&bv;
            }
        }
    }
}

__global__ __launch_bounds__(1024) void k_scan(const int* __restrict__ cnt,
                                               int* __restrict__ ofs, int* __restrict__ cur){
    __shared__ int wsum[16];
    __shared__ int carry_s;
    int tid = threadIdx.x, lane = tid & 63, w = tid >> 6;
    if(tid == 0) carry_s = 0;
    __syncthreads();
    for(int base = 0; base < NN; base += 1024){
        int idx = base + tid;
        int v = (idx < NN) ? cnt[idx] : 0;
        int sc = v;
        #pragma unroll
        for(int o = 1; o < 64; o <<= 1){
            int t = __shfl_up(sc, o);
            if(lane >= o) sc += t;
        }
        if(lane == 63) wsum[w] = sc;
        __syncthreads();
        if(w == 0){
            int ws = (lane < 16) ? wsum[lane] : 0;
            #pragma unroll
            for(int o = 1; o < 16; o <<= 1){
                int t = __shfl_up(ws, o);
                if(lane >= o) ws += t;
            }
            if(lane < 16) wsum[lane] = ws;
        }
        __syncthreads();
        int wbase = (w > 0) ? wsum[w-1] : 0;
        int c = carry_s;
        int excl = c + wbase + sc - v;
        if(idx < NN){ ofs[idx] = excl; cur[idx] = excl; }
        __syncthreads();
        if(tid == 0) carry_s = c + wsum[15];
        __syncthreads();
    }
    if(threadIdx.x == 0) ofs[NN] = carry_s;
}

// ---------------- MFMA GEMM (+ optional fused edge scatter stripe) ----------------
// obf: 0 = fp32 row-H; 2 = fp8 RP-row; 3 = fp8 KV-row K-half; 4 = fp8 KV-row V-half;
//      5 = bf16 packed 512B rows ([c0|c1][c2|pad] per lane)
// When do_scatter: launched as grid(1000, 13); y==12 stripe performs the edge
// scatter (atomic position assign) hidden under the gemm blocks' MFMA work;
// gemm blocks require x<63. spair order within a dst segment is atomic-order-
// dependent (valid for counting sort; only permutes fp-add order in attn).
struct GemmP {
    const u16* wt[4];
    const float* bias[4];
    void* out[4];
    int obf[4];
};
__global__ __launch_bounds__(256) void k_gemm(const u16* __restrict__ A, GemmP P,
                        const int* __restrict__ esrc, const int* __restrict__ edst,
                        const int* __restrict__ etype, const int* __restrict__ nbatch,
                        int* __restrict__ cur, int2* __restrict__ spair,
                        int4* __restrict__ eprep, int do_scatter){
    if(do_scatter && blockIdx.y == 12){
        int e = blockIdx.x*256 + threadIdx.x;
        if(e < NE){
            int s = esrc[e], d = edst[e];
            int ct = (nbatch[s]*VEt + etype[e])*KVR;
            int pos = atomicAdd(&cur[d], 1);
            int2 se; se.x = s*KVR; se.y = ct;
            spair[pos] = se;
            eprep[e] = make_int4(s*RP, d*RP, ct, 0);
        }
        return;
    }
    if(blockIdx.x >= 63) return;
    int oi = blockIdx.y / 3, nt = blockIdx.y % 3;
    const u16* Wt = P.wt[oi];
    const float* bias = P.bias[oi];
    int wave = rfl(threadIdx.x >> 6), lane = threadIdx.x & 63;
    int quad = lane >> 4, l16 = lane & 15;
    int m0 = blockIdx.x*256 + wave*64;
    int n0 = nt*64;
    facc_t acc[4][4];
    #pragma unroll
    for(int i = 0; i < 4; i++)
        #pragma unroll
        for(int j = 0; j < 4; j++){ acc[i][j][0]=0.f; acc[i][j][1]=0.f; acc[i][j][2]=0.f; acc[i][j][3]=0.f; }
    #pragma unroll
    for(int kc = 0; kc < 6; kc++){
        int kb = kc*32 + quad*8;
        bfrag_t af[4], bg[4];
        #pragma unroll
        for(int i = 0; i < 4; i++) af[i] = *(const bfrag_t*)(A  + (size_t)(m0 + i*16 + l16)*H + kb);
        #pragma unroll
        for(int j = 0; j < 4; j++) bg[j] = *(const bfrag_t*)(Wt + (size_t)(n0 + j*16 + l16)*H + kb);
        #pragma unroll
        for(int i = 0; i < 4; i++)
            #pragma unroll
            for(int j = 0; j < 4; j++)
                acc[i][j] = __builtin_amdgcn_mfma_f32_16x16x32_bf16(af[i], bg[j], acc[i][j], 0, 0, 0);
    }
    float bv[4];
    #pragma unroll
    for(int j = 0; j < 4; j++) bv[j] = bias ? bias[n0 + j*16 + l16] : 0.f;
    int mode = P.obf[oi];
    if(mode == 5){
        u16* outp = (u16*)P.out[oi];
        int hoff[4];
        #pragma unroll
        for(int j = 0; j < 4; j++){
            int c = n0 + j*16 + l16;
            hoff[j] = (c/3)*4 + (c%3);
        }
        #pragma unroll
        for(int i = 0; i < 4; i++){
            int rb = m0 + i*16 + quad*4;
            #pragma unroll
            for(int r = 0; r < 4; r++){
                int row = rb + r;
                if(row < NN){
                    #pragma unroll
                    for(int j = 0; j < 4; j++){
                        bf16 b = f2b(acc[i][j][r] + bv[j]);
                        outp[(size_t)row*256 + hoff[j]] = *(u16*)&b;
                    }
                }
            }
        }
    } else if(mode != 0){
        u8* out = (u8*)P.out[oi];
        int rstride = (mode == 2) ? RP : KVR;
        int mult    = (mode == 2) ? 4  : 8;
        int koff    = (mode == 4) ? 4  : 0;
        int byteoff[4];
        #pragma unroll
        for(int j = 0; j < 4; j++){
            int c = n0 + j*16 + l16;
            byteoff[j] = (c/3)*mult + (c%3) + koff;
        }
        #pragma unroll
        for(int i = 0; i < 4; i++){
            int rb = m0 + i*16 + quad*4;
            #pragma unroll
            for(int r = 0; r < 4; r++){
                int row = rb + r;
                if(row < NN){
                    #pragma unroll
                    for(int j = 0; j < 4; j++)
                        out[(size_t)row*rstride + byteoff[j]] = (u8)enc8(acc[i][j][r] + bv[j]);
                }
            }
        }
    } else {
        float* out = (float*)P.out[oi];
        #pragma unroll
        for(int i = 0; i < 4; i++){
            int rb = m0 + i*16 + quad*4;
            #pragma unroll
            for(int r = 0; r < 4; r++){
                int row = rb + r;
                if(row < NN){
                    #pragma unroll
                    for(int j = 0; j < 4; j++)
                        out[(size_t)row*H + n0 + j*16 + l16] = acc[i][j][r] + bv[j];
                }
            }
        }
    }
}

// ---------------- fused attention + gate + LN; pipelined, packed decode ----------------
// Qb: bf16 packed 512B rows; KVb: 512B fp8 rows; etab: bf16 512B rows
__global__ __launch_bounds__(256) void k_attn(
    const u8* __restrict__ Qb, const u8* __restrict__ KVb,
    const float* __restrict__ XR,
    const u16* __restrict__ etab, const int* __restrict__ ofs,
    const int2* __restrict__ spair,
    const float* __restrict__ wb, const float* __restrict__ lng, const float* __restrict__ lnb,
    float* __restrict__ x, u16* __restrict__ xb)
{
    int wv = rfl(threadIdx.x >> 6);
    int n = blockIdx.x*4 + wv;
    int lane = threadIdx.x & 63;
    int lane8 = lane*8;
    int ch = lane*3;
    size_t base = (size_t)n*H + ch;
    const float scale = 0.14433756729740646f;   // 1/sqrt(48)
    u32x2 qw = *(const u32x2*)(Qb + (size_t)n*512 + lane8);
    float q0 = __uint_as_float(qw.x << 16);
    float q1 = __uint_as_float(qw.x & 0xffff0000u);
    float q2 = __uint_as_float(qw.y << 16);
    int p0 = ofs[n], p1 = ofs[n+1];
    float lac[4]  = {0.f,0.f,0.f,0.f};
    float ac0[4]  = {0.f,0.f,0.f,0.f};
    float ac1[4]  = {0.f,0.f,0.f,0.f};
    float ac2[4]  = {0.f,0.f,0.f,0.f};
    const u8* etb = (const u8*)etab;
    int p = p0;
    u32x2 kvc[4], ewc[4];
    bool have = (p + 3 < p1);
    if(have){
        #pragma unroll
        for(int t = 0; t < 4; t++){
            int2 se = spair[p+t];
            kvc[t] = *(const u32x2*)(KVb + se.x + lane8);
            ewc[t] = *(const u32x2*)(etb + se.y + lane8);
        }
    }
    while(have){
        int pn = p + 4;
        bool more = (pn + 3 < p1);
        u32x2 kvn[4], ewn[4];
        if(more){
            #pragma unroll
            for(int t = 0; t < 4; t++){
                int2 se = spair[pn+t];
                kvn[t] = *(const u32x2*)(KVb + se.x + lane8);
                ewn[t] = *(const u32x2*)(etb + se.y + lane8);
            }
        }
        float e0[4], e1[4], e2[4], tt[4];
        #pragma unroll
        for(int t = 0; t < 4; t++){
            e0[t] = __uint_as_float(ewc[t].x << 16);
            e1[t] = __uint_as_float(ewc[t].x & 0xffff0000u);
            e2[t] = __uint_as_float(ewc[t].y << 16);
            f2v k01 = dec8pk01(kvc[t].x);
            float k2 = dec8s<2>(kvc[t].x);
            tt[t] = q0*(k01.x+e0[t]) + q1*(k01.y+e1[t]) + q2*(k2+e2[t]);
        }
        #pragma unroll
        for(int o = 1; o <= 8; o <<= 1){
            #pragma unroll
            for(int t = 0; t < 4; t++) tt[t] += __shfl_xor(tt[t], o);
        }
        #pragma unroll
        for(int t = 0; t < 4; t++){
            float sc = fminf(fmaxf(tt[t]*scale, -60.f), 60.f);
            float pw = __expf(sc);
            f2v v01 = dec8pk01(kvc[t].y);
            float v2 = dec8s<2>(kvc[t].y);
            lac[t] += pw;
            ac0[t] += pw*(v01.x+e0[t]);
            ac1[t] += pw*(v01.y+e1[t]);
            ac2[t] += pw*(v2+e2[t]);
        }
        if(more){
            #pragma unroll
            for(int t = 0; t < 4; t++){ kvc[t] = kvn[t]; ewc[t] = ewn[t]; }
        }
        p = pn;
        have = more;
    }
    for(; p < p1; p++){
        int soA = spair[p].x, eoA = spair[p].y;
        u32x2 kvA = *(const u32x2*)(KVb + soA + lane8);
        u32x2 ewA = *(const u32x2*)(etb + eoA + lane8);
        float e0A = __uint_as_float(ewA.x << 16);
        float e1A = __uint_as_float(ewA.x & 0xffff0000u);
        float e2A = __uint_as_float(ewA.y << 16);
        f2v k01 = dec8pk01(kvA.x);
        float k2 = dec8s<2>(kvA.x);
        float tA = q0*(k01.x+e0A) + q1*(k01.y+e1A) + q2*(k2+e2A);
        tA += __shfl_xor(tA,1); tA += __shfl_xor(tA,2); tA += __shfl_xor(tA,4); tA += __shfl_xor(tA,8);
        float sc = fminf(fmaxf(tA*scale, -60.f), 60.f);
        float pw = __expf(sc);
        f2v v01 = dec8pk01(kvA.y);
        float v2 = dec8s<2>(kvA.y);
        lac[0] += pw;
        ac0[0] += pw*(v01.x+e0A);
        ac1[0] += pw*(v01.y+e1A);
        ac2[0] += pw*(v2+e2A);
    }
    float l  = (lac[0]+lac[1]) + (lac[2]+lac[3]);
    float a0 = (ac0[0]+ac0[1]) + (ac0[2]+ac0[3]);
    float a1 = (ac1[0]+ac1[1]) + (ac1[2]+ac1[3]);
    float a2 = (ac2[0]+ac2[1]) + (ac2[2]+ac2[3]);
    float inv = (p1 > p0) ? 1.f/l : 0.f;
    float o0 = a0*inv, o1 = a1*inv, o2 = a2*inv;
    float xr0 = XR[base], xr1 = XR[base+1], xr2 = XR[base+2];
    float sd = o0*wb[ch]  + o1*wb[ch+1]  + o2*wb[ch+2]
             + xr0*wb[H+ch] + xr1*wb[H+ch+1] + xr2*wb[H+ch+2]
             + (o0-xr0)*wb[2*H+ch] + (o1-xr1)*wb[2*H+ch+1] + (o2-xr2)*wb[2*H+ch+2];
    sd += __shfl_xor(sd,1); sd += __shfl_xor(sd,2); sd += __shfl_xor(sd,4);
    sd += __shfl_xor(sd,8); sd += __shfl_xor(sd,16); sd += __shfl_xor(sd,32);
    float beta = 1.f/(1.f + __expf(-sd));
    float h0 = beta*xr0 + (1.f-beta)*o0;
    float h1 = beta*xr1 + (1.f-beta)*o1;
    float h2 = beta*xr2 + (1.f-beta)*o2;
    float y0 = x[base] + h0, y1 = x[base+1] + h1, y2 = x[base+2] + h2;
    float s3 = y0 + y1 + y2;
    float q3 = y0*y0 + y1*y1 + y2*y2;
    #pragma unroll
    for(int o = 1; o <= 32; o <<= 1){
        s3 += __shfl_xor(s3, o);
        q3 += __shfl_xor(q3, o);
    }
    float mean = s3 * (1.f/H);
    float var = fmaxf(q3*(1.f/H) - mean*mean, 0.f);
    float rs = rsqrtf(var + 1e-5f);
    float d0 = y0-mean, d1 = y1-mean, d2 = y2-mean;
    float z0 = d0*rs*lng[ch]   + lnb[ch];
    float z1 = d1*rs*lng[ch+1] + lnb[ch+1];
    float z2 = d2*rs*lng[ch+2] + lnb[ch+2];
    x[base] = z0; x[base+1] = z1; x[base+2] = z2;
    bf16 t0 = f2b(z0), t1 = f2b(z1), t2 = f2b(z2);
    xb[base] = *(u16*)&t0; xb[base+1] = *(u16*)&t1; xb[base+2] = *(u16*)&t2;
}

// ---------------- node logits: MFMA (M=16128, N=32, K=192), A = xb bf16 ----------------
__global__ __launch_bounds__(256) void k_nodeout(const u16* __restrict__ A, const u16* __restrict__ Wt,
                                                 const float* __restrict__ b, float* __restrict__ out){
    int wave = rfl(threadIdx.x >> 6), lane = threadIdx.x & 63;
    int quad = lane >> 4, l16 = lane & 15;
    int m0 = blockIdx.x*256 + wave*64;
    facc_t acc[4][2];
    #pragma unroll
    for(int i = 0; i < 4; i++)
        #pragma unroll
        for(int j = 0; j < 2; j++){ acc[i][j][0]=0.f; acc[i][j][1]=0.f; acc[i][j][2]=0.f; acc[i][j][3]=0.f; }
    #pragma unroll
    for(int kc = 0; kc < 6; kc++){
        int kb = kc*32 + quad*8;
        bfrag_t af[4], bg[2];
        #pragma unroll
        for(int i = 0; i < 4; i++) af[i] = *(const bfrag_t*)(A  + (size_t)(m0 + i*16 + l16)*H + kb);
        #pragma unroll
        for(int j = 0; j < 2; j++) bg[j] = *(const bfrag_t*)(Wt + (size_t)(j*16 + l16)*H + kb);
        #pragma unroll
        for(int i = 0; i < 4; i++)
            #pragma unroll
            for(int j = 0; j < 2; j++)
                acc[i][j] = __builtin_amdgcn_mfma_f32_16x16x32_bf16(af[i], bg[j], acc[i][j], 0, 0, 0);
    }
    float bv[2];
    #pragma unroll
    for(int j = 0; j < 2; j++) bv[j] = b[j*16 + l16];
    #pragma unroll
    for(int i = 0; i < 4; i++){
        int rb = m0 + i*16 + quad*4;
        #pragma unroll
        for(int r = 0; r < 4; r++){
            int row = rb + r;
            if(row < NN){
                #pragma unroll
                for(int j = 0; j < 2; j++)
                    out[(size_t)row*32 + j*16 + l16] = acc[i][j][r] + bv[j];
            }
        }
    }
}

// ---------------- edge logits: eprep-driven gather+silu -> LDS bf16 -> MFMA ----------------
__global__ __launch_bounds__(256) void k_edgemlp(
    const int4* __restrict__ eprep,
    const u8* __restrict__ xs1, const u8* __restrict__ xd1, const u16* __restrict__ ctab,
    const u16* __restrict__ w2t, const float* __restrict__ b2p, float* __restrict__ out)
{
    __shared__ u16 hbuf[4][16][200];    // [wave][edge][192 bf16 + 8 pad]
    int wave = rfl(threadIdx.x >> 6);
    int lane = threadIdx.x & 63;
    int lane8 = lane*8;
    int l16 = lane & 15, quad = lane >> 4;
    int wid = blockIdx.x*4 + wave;
    int e0 = wid*EML;
    const u8* ctb = (const u8*)ctab;
    bfrag_t bg[6];
    #pragma unroll
    for(int kc = 0; kc < 6; kc++)
        bg[kc] = *(const bfrag_t*)(w2t + (size_t)l16*192 + kc*32 + quad*8);
    for(int eb = 0; eb < EML; eb += 2){
        int4 epX = eprep[e0 + eb];
        int4 epY = eprep[e0 + eb + 1];
        u32 awX = *(const u32*)(xs1 + epX.x + lane*4);
        u32 awY = *(const u32*)(xs1 + epY.x + lane*4);
        u32 bwX = *(const u32*)(xd1 + epX.y + lane*4);
        u32 bwY = *(const u32*)(xd1 + epY.y + lane*4);
        u32x2 cwX = *(const u32x2*)(ctb + epX.z + lane8);
        u32x2 cwY = *(const u32x2*)(ctb + epY.z + lane8);
        float cfX0 = __uint_as_float(cwX.x << 16);
        float cfX1 = __uint_as_float(cwX.x & 0xffff0000u);
        float cfX2 = __uint_as_float(cwX.y << 16);
        float cfY0 = __uint_as_float(cwY.x << 16);
        float cfY1 = __uint_as_float(cwY.x & 0xffff0000u);
        float cfY2 = __uint_as_float(cwY.y << 16);
        f2v aX = dec8pk01(awX), bX = dec8pk01(bwX);
        f2v aY = dec8pk01(awY), bY = dec8pk01(bwY);
        float aX2 = dec8s<2>(awX), bX2 = dec8s<2>(bwX);
        float aY2 = dec8s<2>(awY), bY2 = dec8s<2>(bwY);
        float hX0, hX1, hX2, hY0, hY1, hY2;
        { float v = aX.x+bX.x+cfX0; hX0 = v*frcp(1.f+__expf(-v)); }
        { float v = aX.y+bX.y+cfX1; hX1 = v*frcp(1.f+__expf(-v)); }
        { float v = aX2 +bX2 +cfX2; hX2 = v*frcp(1.f+__expf(-v)); }
        { float v = aY.x+bY.x+cfY0; hY0 = v*frcp(1.f+__expf(-v)); }
        { float v = aY.y+bY.y+cfY1; hY1 = v*frcp(1.f+__expf(-v)); }
        { float v = aY2 +bY2 +cfY2; hY2 = v*frcp(1.f+__expf(-v)); }
        u16* rowX = &hbuf[wave][eb][0];
        u16* rowY = &hbuf[wave][eb+1][0];
        bf16 x0 = f2b(hX0), x1 = f2b(hX1), x2 = f2b(hX2);
        bf16 y0 = f2b(hY0), y1 = f2b(hY1), y2 = f2b(hY2);
        rowX[lane*3+0] = *(u16*)&x0; rowX[lane*3+1] = *(u16*)&x1; rowX[lane*3+2] = *(u16*)&x2;
        rowY[lane*3+0] = *(u16*)&y0; rowY[lane*3+1] = *(u16*)&y1; rowY[lane*3+2] = *(u16*)&y2;
    }
    __syncthreads();
    facc_t acc;
    acc[0]=0.f; acc[1]=0.f; acc[2]=0.f; acc[3]=0.f;
    #pragma unroll
    for(int kc = 0; kc < 6; kc++){
        bfrag_t af = *(const bfrag_t*)&hbuf[wave][l16][kc*32 + quad*8];
        acc = __builtin_amdgcn_mfma_f32_16x16x32_bf16(af, bg[kc], acc, 0, 0, 0);
    }
    if(l16 < 8){
        float bo = b2p[l16];
        #pragma unroll
        for(int r = 0; r < 4; r++){
            int e = e0 + quad*4 + r;
            out[(size_t)e*8 + l16] = acc[r] + bo;
        }
    }
}

extern "C" void kernel_launch(void* const* d_in, const int* in_sizes, int n_in,
                              void* d_out, int out_size, void* d_ws, size_t ws_size,
                              hipStream_t stream)
{
    {
        int bad = -1;
        if(n_in != 31) bad = 100;
        else {
            const int chk_idx[9] = {0, 7, 16, 21, 23, 26, 27, 29, 30};
            const int chk_sz [9] = {32*H, NL*HH, NL*3*H, 4*HH, H*8, NE, 2*NE, NN, NBATCH};
            for(int i = 0; i < 9; i++) if(in_sizes[chk_idx[i]] != chk_sz[i]){ bad = chk_idx[i]; break; }
        }
        if(bad >= 0){ k_sentinel<<<1,1,0,stream>>>((float*)d_out, 20000.f + 256.f*bad); return; }
        if(out_size != NN*32 + NE*8){ k_sentinel<<<1,1,0,stream>>>((float*)d_out, 30000.f); return; }
    }

    const float* node_emb = (const float*)d_in[0];
    const float* edge_emb = (const float*)d_in[1];
    const float* time_w1  = (const float*)d_in[2];
    const float* time_b1  = (const float*)d_in[3];
    const float* time_w2  = (const float*)d_in[4];
    const float* time_b2  = (const float*)d_in[5];
    const float* mask_emb = (const float*)d_in[6];
    const float* wq       = (const float*)d_in[7];
    const float* bq       = (const float*)d_in[8];
    const float* wk       = (const float*)d_in[9];
    const float* bk       = (const float*)d_in[10];
    const float* wv       = (const float*)d_in[11];
    const float* bv       = (const float*)d_in[12];
    const float* we       = (const float*)d_in[13];
    const float* wskip    = (const float*)d_in[14];
    const float* bskip    = (const float*)d_in[15];
    const float* wbeta    = (const float*)d_in[16];
    const float* ln_g     = (const float*)d_in[17];
    const float* ln_b     = (const float*)d_in[18];
    const float* now      = (const float*)d_in[19];
    const float* nob      = (const float*)d_in[20];
    const float* ew1      = (const float*)d_in[21];
    const float* eb1      = (const float*)d_in[22];
    const float* ew2      = (const float*)d_in[23];
    const float* eb2      = (const float*)d_in[24];
    const int* node_type  = (const int*)d_in[25];
    const int* edge_type  = (const int*)d_in[26];
    const int* edge_index = (const int*)d_in[27];
    const int* edit_mask  = (const int*)d_in[28];
    const int* node_batch = (const int*)d_in[29];
    const int* t_graph    = (const int*)d_in[30];
    const int* esrc = edge_index;
    const int* edst = edge_index + NE;

    char* wsb = (char*)d_ws;
    size_t off = 0;
    auto take = [&](size_t bytes) -> char* {
        char* r = wsb + off;
        off += (bytes + 255) & ~(size_t)255;
        return r;
    };
    float* tvec = (float*)take((size_t)NBATCH*H*4);
    float* x    = (float*)take((size_t)NN*H*4);
    u16*   xb   = (u16*)  take((size_t)NPAD*H*2);
    u8*    Qb   = (u8*)   take((size_t)NN*512);
    u8*    KVb  = (u8*)   take((size_t)NN*KVR);
    float* XR   = (float*)take((size_t)NN*H*4);
    u8*    xs1  = (u8*)   take((size_t)NN*RP);
    u8*    xd1  = (u8*)   take((size_t)NN*RP);
    u16*   etab = (u16*)  take((size_t)NL*64*KVR);
    u16*   ctab = (u16*)  take((size_t)64*KVR);
    u16*   wt   = (u16*)  take((size_t)(18*HH + 32*192 + 16*192)*2);
    int* cnt    = (int*)  take((size_t)(NN+1)*4);
    int* offa   = (int*)  take((size_t)(NN+1)*4);
    int* cur    = (int*)  take((size_t)(NN+1)*4);
    int2* spair = (int2*) take((size_t)NE*8);
    int4* eprep = (int4*) take((size_t)NE*16);

    if(ws_size < off){
        k_sentinel<<<1,1,0,stream>>>((float*)d_out, 10000.f + (float)(ws_size >> 20));
        return;
    }

    u16* w32t = wt + (size_t)18*HH;          // [32][192] bf16 (node_out_w^T)
    u16* w2t  = w32t + 32*192;               // [16][192] bf16 (edge_w2^T, zero-padded)

    k_prep0<<<231, 256, 0, stream>>>(wq, wk, wv, wskip, ew1, now, ew2, wt,
                                     t_graph, time_w1, time_b1, time_w2, time_b2, tvec, cnt);
    k_prep1<<<13320, 256, 0, stream>>>(node_emb, mask_emb, tvec, node_type, edit_mask, node_batch,
                                       x, xb, edst, cnt, edge_emb, we, ew1, eb1, etab, ctab);
    k_scan<<<1, 1024, 0, stream>>>(cnt, offa, cur);

    for(int l = 0; l < NL; l++){
        GemmP P;
        P.wt[0] = wt + (size_t)(0  + l)*HH;  P.bias[0] = bq   + (size_t)l*H;  P.out[0] = Qb;  P.obf[0] = 5;
        P.wt[1] = wt + (size_t)(4  + l)*HH;  P.bias[1] = bk   + (size_t)l*H;  P.out[1] = KVb; P.obf[1] = 3;
        P.wt[2] = wt + (size_t)(8  + l)*HH;  P.bias[2] = bv   + (size_t)l*H;  P.out[2] = KVb; P.obf[2] = 4;
        P.wt[3] = wt + (size_t)(12 + l)*HH;  P.bias[3] = bskip+ (size_t)l*H;  P.out[3] = XR;  P.obf[3] = 0;
        if(l == 0){
            // layer-0 gemm carries the edge scatter in a y==12 stripe (hides atomic drain)
            k_gemm<<<dim3(NE/256, 13), 256, 0, stream>>>(xb, P, esrc, edst, edge_type,
                                                         node_batch, cur, spair, eprep, 1);
        } else {
            k_gemm<<<dim3(63, 12), 256, 0, stream>>>(xb, P, esrc, edst, edge_type,
                                                     node_batch, cur, spair, eprep, 0);
        }
        k_attn<<<NN/4, 256, 0, stream>>>(Qb, KVb, XR, etab + (size_t)l*64*256, offa, spair,
                                         wbeta + (size_t)l*3*H, ln_g + (size_t)l*H,
                                         ln_b + (size_t)l*H, x, xb);
    }
    {
        GemmP P;
        P.wt[0] = wt + (size_t)16*HH; P.bias[0] = nullptr; P.out[0] = xs1; P.obf[0] = 2;
        P.wt[1] = wt + (size_t)17*HH; P.bias[1] = nullptr; P.out[1] = xd1; P.obf[1] = 2;
        P.wt[2] = P.wt[0]; P.bias[2] = nullptr; P.out[2] = xs1; P.obf[2] = 2;
        P.wt[3] = P.wt[0]; P.bias[3] = nullptr; P.out[3] = xs1; P.obf[3] = 2;
        k_gemm<<<dim3(63, 6), 256, 0, stream>>>(xb, P, esrc, edst, edge_type,
                                                node_batch, cur, spair, eprep, 0);
    }
    k_nodeout<<<63, 256, 0, stream>>>(xb, w32t, nob, (float*)d_out);
    k_edgemlp<<<NE/(4*EML), 256, 0, stream>>>(eprep, xs1, xd1, ctab,
                                              w2t, eb2, (float*)d_out + (size_t)NN*32);
}